// Round 15
// baseline (6595.676 us; speedup 1.0000x reference)
//
#include <hip/hip_runtime.h>
#include <math.h>

// Problem constants
#define NPTS   65536
#define NBATCH 4
#define KCP    1024      // NCP centers
#define DM     256
#define FFD    1024
#define EDIM   8192      // E
#define N3E    24576     // 3*E

// FPS decomposition: 16 blocks/batch x 256 threads (4 waves); 64 publisher-waves
// per batch, each wave owns 1024 points (16/thread) held in registers.
#define FPS_NBLK 16
#define FPS_THR  256
#define FPS_PPT  16
#define GPUB     8       // keys published per wave per round (last one = bound) [empirical optimum]
#define HARV_MAX 16      // max winners harvested per global sync round
#define RING     16      // mailbox ring depth (rounds)
#define TSPLIT   512     // phase-0/phase-1 split point (2-dispatch fps)

typedef __attribute__((ext_vector_type(8))) short short8v;
typedef __attribute__((ext_vector_type(4))) short short4v;
typedef __attribute__((ext_vector_type(4))) float float4v;

__device__ __forceinline__ unsigned long long umaxll(unsigned long long a, unsigned long long b) {
  return a > b ? a : b;
}

__device__ __forceinline__ short bf16rn(float f) {
  unsigned u = __float_as_uint(f);
  return (short)((u + 0x7FFFu + ((u >> 16) & 1u)) >> 16);
}

// ---------------------------------------------------------------- global min/max (for L)
__global__ __launch_bounds__(256) void redmm_kernel(const float* __restrict__ v, int n,
                                                    float* __restrict__ pmax, float* __restrict__ pmin) {
  float mx = -INFINITY, mn = INFINITY;
  for (int i = blockIdx.x * 256 + threadIdx.x; i < n; i += gridDim.x * 256) {
    float x = v[i]; mx = fmaxf(mx, x); mn = fminf(mn, x);
  }
#pragma unroll
  for (int off = 32; off >= 1; off >>= 1) {
    mx = fmaxf(mx, __shfl_xor(mx, off, 64));
    mn = fminf(mn, __shfl_xor(mn, off, 64));
  }
  __shared__ float smx[4], smn[4];
  int lane = threadIdx.x & 63, w = threadIdx.x >> 6;
  if (lane == 0) { smx[w] = mx; smn[w] = mn; }
  __syncthreads();
  if (threadIdx.x == 0) {
    pmax[blockIdx.x] = fmaxf(fmaxf(smx[0], smx[1]), fmaxf(smx[2], smx[3]));
    pmin[blockIdx.x] = fminf(fminf(smn[0], smn[1]), fminf(smn[2], smn[3]));
  }
}

__global__ __launch_bounds__(256) void redfin_kernel(const float* __restrict__ pmax,
                                                     const float* __restrict__ pmin, int nb,
                                                     float* __restrict__ Lv) {
  float mx = -INFINITY, mn = INFINITY;
  for (int i = threadIdx.x; i < nb; i += 256) { mx = fmaxf(mx, pmax[i]); mn = fminf(mn, pmin[i]); }
#pragma unroll
  for (int off = 32; off >= 1; off >>= 1) {
    mx = fmaxf(mx, __shfl_xor(mx, off, 64));
    mn = fminf(mn, __shfl_xor(mn, off, 64));
  }
  __shared__ float smx[4], smn[4];
  int lane = threadIdx.x & 63, w = threadIdx.x >> 6;
  if (lane == 0) { smx[w] = mx; smn[w] = mn; }
  __syncthreads();
  if (threadIdx.x == 0) {
    mx = fmaxf(fmaxf(smx[0], smx[1]), fmaxf(smx[2], smx[3]));
    mn = fminf(fminf(smn[0], smn[1]), fminf(smn[2], smn[3]));
    Lv[0] = __fsub_rn(mx, mn);
  }
}

// ---------------------------------------------------------------- FPS: top-8 harvesting, single-poller-per-block
__global__ __launch_bounds__(FPS_THR, 1) void fps_kernel(const float* __restrict__ pc,
                                                         float* __restrict__ centers,
                                                         unsigned* __restrict__ tags,
                                                         unsigned long long* __restrict__ keys,
                                                         float* __restrict__ mindbuf,
                                                         int* __restrict__ state,
                                                         int phase) {
  const int blk = blockIdx.x;
  const int b = blk / FPS_NBLK, bb = blk % FPS_NBLK;
  const int tid = threadIdx.x;
  const int lane = tid & 63, wv = tid >> 6;
  const int wvg = bb * 4 + wv;                 // wave id in batch: 0..63
  const float* pcb = pc + (size_t)b * NPTS * 3;

  __shared__ float kpts[96];
  __shared__ float wlds[2][HARV_MAX][3];
  __shared__ int hcnt[2];

  float px[FPS_PPT], py[FPS_PPT], pz[FPS_PPT], mind[FPS_PPT];
  const int gbase = wvg * 1024;                // 1024 points per wave
#pragma unroll
  for (int i = 0; i < FPS_PPT; ++i) {
    int g = gbase + i * 64 + lane;
    px[i] = pcb[3 * g]; py[i] = pcb[3 * g + 1]; pz[i] = pcb[3 * g + 2];
  }

  unsigned* const tagb = tags + (size_t)b * RING * 64;                   // [RING][64] u32
  unsigned long long* const keyb = keys + (size_t)b * RING * 64 * GPUB;  // [RING][64][GPUB]
  float* const mb = mindbuf + ((size_t)b * 64 + wvg) * FPS_PPT * 64;

  int t, r;
  if (phase == 0) {
    for (int i = tid; i < 96; i += FPS_THR) kpts[i] = pcb[i];
    __syncthreads();   // kpts ready
    // --- round 1: density over first 32 points (IEEE f32, op-for-op) -> center 0
    unsigned long long bk = 0ull;
#pragma unroll
    for (int i = 0; i < FPS_PPT; ++i) {
      float acc = 0.f;
      for (int j = 0; j < 32; ++j) {
        float dx = __fsub_rn(px[i], kpts[3 * j]);
        float dy = __fsub_rn(py[i], kpts[3 * j + 1]);
        float dz = __fsub_rn(pz[i], kpts[3 * j + 2]);
        float ss = __fadd_rn(__fadd_rn(__fmul_rn(dx, dx), __fmul_rn(dy, dy)), __fmul_rn(dz, dz));
        float d = __fsqrt_rn(ss);
        float dd = __fadd_rn(__fmul_rn(d, d), 1e-6f);
        acc = __fadd_rn(acc, expf(__fdiv_rn(-0.02f, dd)));
      }
      float dens = __fdiv_rn(acc, 32.f);
      int g = gbase + i * 64 + lane;
      bk = umaxll(bk, ((unsigned long long)__float_as_uint(dens) << 32) | (unsigned int)(~g));
    }
#pragma unroll
    for (int off = 1; off < 64; off <<= 1) bk = umaxll(bk, __shfl_xor(bk, off, 64));
    if (lane == 0) {
      keyb[(size_t)(1 & (RING - 1)) * 64 * GPUB + wvg * GPUB] = bk;
      __hip_atomic_store(&tagb[(1 & (RING - 1)) * 64 + wvg], 1u, __ATOMIC_RELEASE, __HIP_MEMORY_SCOPE_AGENT);
    }
    unsigned tag;
    do {
      tag = __hip_atomic_load(&tagb[(1 & (RING - 1)) * 64 + lane], __ATOMIC_ACQUIRE, __HIP_MEMORY_SCOPE_AGENT);
    } while (__any(tag != 1u));
    unsigned long long k2 = __hip_atomic_load(&keyb[(size_t)(1 & (RING - 1)) * 64 * GPUB + lane * GPUB],
                                              __ATOMIC_RELAXED, __HIP_MEMORY_SCOPE_AGENT);
#pragma unroll
    for (int off = 1; off < 64; off <<= 1) k2 = umaxll(k2, __shfl_xor(k2, off, 64));
    int widx = (int)(~(unsigned)(k2 & 0xFFFFFFFFull));
    float wx = pcb[3 * widx], wy = pcb[3 * widx + 1], wz = pcb[3 * widx + 2];
    if (wvg == 0 && lane == 0) {
      centers[(size_t)b * KCP * 3 + 0] = wx;
      centers[(size_t)b * KCP * 3 + 1] = wy;
      centers[(size_t)b * KCP * 3 + 2] = wz;
    }
#pragma unroll
    for (int i = 0; i < FPS_PPT; ++i) {
      float dx = __fsub_rn(px[i], wx), dy = __fsub_rn(py[i], wy), dz = __fsub_rn(pz[i], wz);
      mind[i] = __fsqrt_rn(__fadd_rn(__fadd_rn(__fmul_rn(dx, dx), __fmul_rn(dy, dy)), __fmul_rn(dz, dz)));
    }
    t = 1; r = 2;
  } else {
    r = state[b * 2]; t = state[b * 2 + 1];
#pragma unroll
    for (int i = 0; i < FPS_PPT; ++i) mind[i] = mb[i * 64 + lane];
  }

  const int tend = phase ? KCP : TSPLIT;
  while (t < tend) {
    // every wave: fresh keys + extract top-8 (keys only)
    unsigned long long tk[FPS_PPT];
#pragma unroll
    for (int i = 0; i < FPS_PPT; ++i) {
      int g = gbase + i * 64 + lane;
      tk[i] = ((unsigned long long)__float_as_uint(mind[i]) << 32) | (unsigned int)(~g);
    }
    unsigned long long ek[GPUB];
#pragma unroll
    for (int g = 0; g < GPUB; ++g) {
      unsigned long long lbk = 0ull;
#pragma unroll
      for (int i = 0; i < FPS_PPT; ++i) lbk = umaxll(lbk, tk[i]);
      unsigned long long wk = lbk;
#pragma unroll
      for (int off = 1; off < 64; off <<= 1) wk = umaxll(wk, __shfl_xor(wk, off, 64));
      ek[g] = wk;
#pragma unroll
      for (int i = 0; i < FPS_PPT; ++i)
        if (tk[i] == wk) tk[i] = 0ull;
    }
    const int ri = r & (RING - 1);
    if (lane == 0) {
      unsigned long long* sp = keyb + ((size_t)ri * 64 + wvg) * GPUB;
#pragma unroll
      for (int g = 0; g < GPUB; ++g)
        __hip_atomic_store(&sp[g], ek[g], __ATOMIC_RELAXED, __HIP_MEMORY_SCOPE_AGENT);
      __hip_atomic_store(&tagb[ri * 64 + wvg], (unsigned)r, __ATOMIC_RELEASE, __HIP_MEMORY_SCOPE_AGENT);
    }

    if (wv == 0) {
      // single poller: wave 0 of each block
      unsigned tag;
      do {
        tag = __hip_atomic_load(&tagb[ri * 64 + lane], __ATOMIC_ACQUIRE, __HIP_MEMORY_SCOPE_AGENT);
      } while (__any(tag != (unsigned)r));
      const unsigned long long* pl = keyb + ((size_t)ri * 64 + lane) * GPUB;
      unsigned long long ck[GPUB];
#pragma unroll
      for (int e = 0; e < GPUB; ++e)
        ck[e] = __hip_atomic_load(&pl[e], __ATOMIC_RELAXED, __HIP_MEMORY_SCOPE_AGENT);
      float cx[GPUB], cy[GPUB], cz[GPUB];
#pragma unroll
      for (int e = 0; e < GPUB; ++e) {
        int gi = (int)(~(unsigned)(ck[e] & 0xFFFFFFFFull));
        cx[e] = pcb[3 * gi]; cy[e] = pcb[3 * gi + 1]; cz[e] = pcb[3 * gi + 2];
      }
      unsigned long long u = ck[GPUB - 1];
#pragma unroll
      for (int off = 1; off < 64; off <<= 1) u = umaxll(u, __shfl_xor(u, off, 64));
      int h = 0, tl = t;
      while (true) {
        unsigned long long lb = 0ull; float lx = 0.f, ly = 0.f, lz = 0.f;
#pragma unroll
        for (int e = 0; e < GPUB; ++e)
          if (ck[e] > lb) { lb = ck[e]; lx = cx[e]; ly = cy[e]; lz = cz[e]; }
        unsigned long long wk = lb;
#pragma unroll
        for (int off = 1; off < 64; off <<= 1) wk = umaxll(wk, __shfl_xor(wk, off, 64));
        if (h > 0 && wk < u) break;   // h==0 pick is always the true global argmax
        int owner = __ffsll(__ballot(lb == wk)) - 1;
        float wx = __shfl(lx, owner, 64), wy = __shfl(ly, owner, 64), wz = __shfl(lz, owner, 64);
        if (lane == 0) {
          wlds[r & 1][h][0] = wx; wlds[r & 1][h][1] = wy; wlds[r & 1][h][2] = wz;
          if (bb == 0) {
            centers[((size_t)b * KCP + tl) * 3 + 0] = wx;
            centers[((size_t)b * KCP + tl) * 3 + 1] = wy;
            centers[((size_t)b * KCP + tl) * 3 + 2] = wz;
          }
        }
#pragma unroll
        for (int e = 0; e < GPUB; ++e) {
          float dx = __fsub_rn(cx[e], wx), dy = __fsub_rn(cy[e], wy), dz = __fsub_rn(cz[e], wz);
          float d = __fsqrt_rn(__fadd_rn(__fadd_rn(__fmul_rn(dx, dx), __fmul_rn(dy, dy)), __fmul_rn(dz, dz)));
          float ov = __uint_as_float((unsigned)(ck[e] >> 32));
          float nv = fminf(ov, d);
          ck[e] = ((unsigned long long)__float_as_uint(nv) << 32) | (ck[e] & 0xFFFFFFFFull);
        }
        ++h; ++tl;
        if (h == HARV_MAX || tl == KCP) break;
      }
      if (lane == 0) hcnt[r & 1] = h;
    }
    __syncthreads();
    const int h = hcnt[r & 1];
    for (int j = 0; j < h; ++j) {
      float wx = wlds[r & 1][j][0], wy = wlds[r & 1][j][1], wz = wlds[r & 1][j][2];
#pragma unroll
      for (int i = 0; i < FPS_PPT; ++i) {
        float dx = __fsub_rn(px[i], wx), dy = __fsub_rn(py[i], wy), dz = __fsub_rn(pz[i], wz);
        float d = __fsqrt_rn(__fadd_rn(__fadd_rn(__fmul_rn(dx, dx), __fmul_rn(dy, dy)), __fmul_rn(dz, dz)));
        mind[i] = fminf(mind[i], d);
      }
    }
    t += h; ++r;
  }

  if (phase == 0) {
#pragma unroll
    for (int i = 0; i < FPS_PPT; ++i) mb[i * 64 + lane] = mind[i];
    if (bb == 0 && wv == 0 && lane == 0) { state[b * 2] = r; state[b * 2 + 1] = t; }
  }
}

// ---------------------------------------------------------------- point encoder + pos-emb -> x (B,K,256)
__global__ __launch_bounds__(128) void pe_kernel(const float* __restrict__ centers,
                                                 const float* __restrict__ w1, const float* __restrict__ b1,
                                                 const float* __restrict__ w2, const float* __restrict__ b2,
                                                 float* __restrict__ x) {
  const int p = blockIdx.x;      // b*K + k
  const int d = threadIdx.x;     // 0..127
  __shared__ float h[128];
  __shared__ float c[3];
  if (d < 3) c[d] = centers[(size_t)p * 3 + d];
  __syncthreads();
  float hv = b1[d];
#pragma unroll
  for (int j = 0; j < 3; ++j) hv += c[j] * w1[j * 128 + d];
  hv = fmaxf(hv, 0.f);
  h[d] = hv;
  __syncthreads();
  float f = b2[d];
  for (int j = 0; j < 128; ++j) f += h[j] * w2[j * 128 + d];
  x[(size_t)p * 256 + d] = f;
  if (d < 64) {
    float fr = expf(__fmul_rn((float)d, -0.14619587892025696f)); // -ln(10000)/63
    float ssum = 0.f, csum = 0.f;
#pragma unroll
    for (int a = 0; a < 3; ++a) {
      float e = __fmul_rn(c[a], fr);
      ssum += sinf(e); csum += cosf(e);
    }
    x[(size_t)p * 256 + 128 + d] = __fdiv_rn(ssum, 3.f);
    x[(size_t)p * 256 + 192 + d] = __fdiv_rn(csum, 3.f);
  }
}

// ---------------------------------------------------------------- bf16 MFMA GEMM: C = A(M,K)@W(K,N)+bias [relu]
__global__ __launch_bounds__(256) void gemm_mfma_kernel(const float* __restrict__ A,
                                                        const float* __restrict__ W,
                                                        const float* __restrict__ bias,
                                                        float* __restrict__ C,
                                                        int M, int Kd, int Nd, int relu) {
  __shared__ __align__(16) short Al[128][40];
  __shared__ __align__(16) short Wl[128][40];
  const int bm = blockIdx.y * 128, bn = blockIdx.x * 128;
  const int tid = threadIdx.x;
  const int lane = tid & 63, wv = tid >> 6;
  const int wr = wv >> 1, wc = wv & 1;
  const int l15 = lane & 15, lk = lane >> 4;

  float4v acc[4][4];
#pragma unroll
  for (int i = 0; i < 4; ++i)
#pragma unroll
    for (int j = 0; j < 4; ++j) acc[i][j] = (float4v){0.f, 0.f, 0.f, 0.f};

  for (int k0 = 0; k0 < Kd; k0 += 32) {
    __syncthreads();
#pragma unroll
    for (int i = 0; i < 4; ++i) {
      int idx = (i * 256 + tid) * 4;        // 0..4095
      int m = idx >> 5, k = idx & 31;
      float4 v = *(const float4*)&A[(size_t)(bm + m) * Kd + k0 + k];
      short4v s = { bf16rn(v.x), bf16rn(v.y), bf16rn(v.z), bf16rn(v.w) };
      *(short4v*)&Al[m][k] = s;
    }
#pragma unroll
    for (int i = 0; i < 4; ++i) {
      int task = i * 256 + tid;
      int n = task & 127, c = task >> 7;
      short4v s;
#pragma unroll
      for (int j = 0; j < 4; ++j)
        s[j] = bf16rn(W[(size_t)(k0 + c * 4 + j) * Nd + bn + n]);
      *(short4v*)&Wl[n][c * 4] = s;
    }
    __syncthreads();
    short8v af[4], bf[4];
#pragma unroll
    for (int mf = 0; mf < 4; ++mf)
      af[mf] = *(const short8v*)&Al[wr * 64 + mf * 16 + l15][lk * 8];
#pragma unroll
    for (int nf = 0; nf < 4; ++nf)
      bf[nf] = *(const short8v*)&Wl[wc * 64 + nf * 16 + l15][lk * 8];
#pragma unroll
    for (int mf = 0; mf < 4; ++mf)
#pragma unroll
      for (int nf = 0; nf < 4; ++nf)
        acc[mf][nf] = __builtin_amdgcn_mfma_f32_16x16x32_bf16(af[mf], bf[nf], acc[mf][nf], 0, 0, 0);
  }

#pragma unroll
  for (int mf = 0; mf < 4; ++mf) {
    int row = bm + wr * 64 + mf * 16 + lk * 4;
#pragma unroll
    for (int nf = 0; nf < 4; ++nf) {
      int col = bn + wc * 64 + nf * 16 + l15;
      float bv = bias[col];
#pragma unroll
      for (int j = 0; j < 4; ++j) {
        float v = acc[mf][nf][j] + bv;
        if (relu) v = fmaxf(v, 0.f);
        C[(size_t)(row + j) * Nd + col] = v;
      }
    }
  }
}

// ---------------------------------------------------------------- MFMA flash attention (S=1024, dh=32, nh=8)
__global__ __launch_bounds__(256, 1) void flash_mfma_kernel(const float* __restrict__ qkv,
                                                            float* __restrict__ ao) {
  const int qt = blockIdx.x, h = blockIdx.y, b = blockIdx.z;
  const int tid = threadIdx.x;
  const int lane = tid & 63, w = tid >> 6;
  const int l15 = lane & 15, lk = lane >> 4;
  const int q0 = qt * 64;

  __shared__ __align__(16) short Kc[64][40];    // [key][dim]
  __shared__ __align__(16) short Vt[32][72];    // [dim][key] (transposed)
  __shared__ __align__(16) short Plds[4][16][72]; // per-wave [q][key]

  short8v qa;
  {
    const float* qr = qkv + (size_t)(b * 1024 + q0 + w * 16 + l15) * 768 + h * 32 + lk * 8;
    float4 a = *(const float4*)qr;
    float4 c = *(const float4*)(qr + 4);
    qa = (short8v){ bf16rn(a.x), bf16rn(a.y), bf16rn(a.z), bf16rn(a.w),
                    bf16rn(c.x), bf16rn(c.y), bf16rn(c.z), bf16rn(c.w) };
  }

  float4v o0 = (float4v){0.f, 0.f, 0.f, 0.f};
  float4v o1 = (float4v){0.f, 0.f, 0.f, 0.f};
  float m_cur[4] = { -INFINITY, -INFINITY, -INFINITY, -INFINITY };
  float l_part[4] = { 0.f, 0.f, 0.f, 0.f };
  const float scale = 0.17677669529663687f;   // 1/sqrt(32)

  for (int c0 = 0; c0 < 1024; c0 += 64) {
    __syncthreads();
    {
      int key = tid >> 2, dblk = (tid & 3) * 8;
      size_t row = (size_t)(b * 1024 + c0 + key) * 768 + h * 32 + dblk;
      float4 k1 = *(const float4*)&qkv[row + 256];
      float4 k2 = *(const float4*)&qkv[row + 260];
      short8v ks = (short8v){ bf16rn(k1.x), bf16rn(k1.y), bf16rn(k1.z), bf16rn(k1.w),
                              bf16rn(k2.x), bf16rn(k2.y), bf16rn(k2.z), bf16rn(k2.w) };
      *(short8v*)&Kc[key][dblk] = ks;
      float4 v1 = *(const float4*)&qkv[row + 512];
      float4 v2 = *(const float4*)&qkv[row + 516];
      Vt[dblk + 0][key] = bf16rn(v1.x); Vt[dblk + 1][key] = bf16rn(v1.y);
      Vt[dblk + 2][key] = bf16rn(v1.z); Vt[dblk + 3][key] = bf16rn(v1.w);
      Vt[dblk + 4][key] = bf16rn(v2.x); Vt[dblk + 5][key] = bf16rn(v2.y);
      Vt[dblk + 6][key] = bf16rn(v2.z); Vt[dblk + 7][key] = bf16rn(v2.w);
    }
    __syncthreads();

    float4v s[4];
#pragma unroll
    for (int f = 0; f < 4; ++f) {
      short8v kb = *(const short8v*)&Kc[f * 16 + l15][lk * 8];
      float4v z = (float4v){0.f, 0.f, 0.f, 0.f};
      s[f] = __builtin_amdgcn_mfma_f32_16x16x32_bf16(qa, kb, z, 0, 0, 0);
    }
#pragma unroll
    for (int f = 0; f < 4; ++f)
#pragma unroll
      for (int j = 0; j < 4; ++j) s[f][j] *= scale;

    float corr[4];
#pragma unroll
    for (int j = 0; j < 4; ++j) {
      float v = fmaxf(fmaxf(s[0][j], s[1][j]), fmaxf(s[2][j], s[3][j]));
#pragma unroll
      for (int off = 1; off < 16; off <<= 1) v = fmaxf(v, __shfl_xor(v, off, 64));
      float m_new = fmaxf(m_cur[j], v);
      corr[j] = expf(m_cur[j] - m_new);
      m_cur[j] = m_new;
    }
#pragma unroll
    for (int f = 0; f < 4; ++f)
#pragma unroll
      for (int j = 0; j < 4; ++j) {
        float p = expf(s[f][j] - m_cur[j]);
        s[f][j] = p;
        Plds[w][lk * 4 + j][f * 16 + l15] = bf16rn(p);
      }
#pragma unroll
    for (int j = 0; j < 4; ++j) {
      float tsum = s[0][j] + s[1][j] + s[2][j] + s[3][j];
#pragma unroll
      for (int off = 1; off < 16; off <<= 1) tsum += __shfl_xor(tsum, off, 64);
      l_part[j] = l_part[j] * corr[j] + tsum;
      o0[j] *= corr[j];
      o1[j] *= corr[j];
    }
    asm volatile("s_waitcnt lgkmcnt(0)" ::: "memory");
    __builtin_amdgcn_sched_barrier(0);

#pragma unroll
    for (int kb = 0; kb < 2; ++kb) {
      short8v pa = *(const short8v*)&Plds[w][l15][kb * 32 + lk * 8];
      short8v vb0 = *(const short8v*)&Vt[l15][kb * 32 + lk * 8];
      short8v vb1 = *(const short8v*)&Vt[16 + l15][kb * 32 + lk * 8];
      o0 = __builtin_amdgcn_mfma_f32_16x16x32_bf16(pa, vb0, o0, 0, 0, 0);
      o1 = __builtin_amdgcn_mfma_f32_16x16x32_bf16(pa, vb1, o1, 0, 0, 0);
    }
  }

#pragma unroll
  for (int j = 0; j < 4; ++j) {
    float inv = 1.f / l_part[j];
    int q = q0 + w * 16 + lk * 4 + j;
    float* orow = ao + (size_t)(b * 1024 + q) * 256 + h * 32;
    orow[l15] = o0[j] * inv;
    orow[16 + l15] = o1[j] * inv;
  }
}

// ---------------------------------------------------------------- fused residual + LayerNorm (rows of 256)
__global__ __launch_bounds__(256) void ln_kernel(const float* __restrict__ a, const float* __restrict__ r,
                                                 const float* __restrict__ sc, const float* __restrict__ bi,
                                                 float* __restrict__ out) {
  const int row = blockIdx.x * 4 + (threadIdx.x >> 6);
  const int lane = threadIdx.x & 63;
  const float* ar = a + (size_t)row * 256;
  const float* rr = r + (size_t)row * 256;
  float v[4];
#pragma unroll
  for (int i = 0; i < 4; ++i) v[i] = ar[lane + 64 * i] + rr[lane + 64 * i];
  float s = v[0] + v[1] + v[2] + v[3];
#pragma unroll
  for (int off = 32; off >= 1; off >>= 1) s += __shfl_xor(s, off, 64);
  float mean = s * (1.f / 256.f);
  float vs = 0.f;
#pragma unroll
  for (int i = 0; i < 4; ++i) { float d = v[i] - mean; vs += d * d; }
#pragma unroll
  for (int off = 32; off >= 1; off >>= 1) vs += __shfl_xor(vs, off, 64);
  float var = vs * (1.f / 256.f);
  float rstd = 1.f / sqrtf(var + 1e-5f);
  float* orow = out + (size_t)row * 256;
#pragma unroll
  for (int i = 0; i < 4; ++i) {
    int d = lane + 64 * i;
    orow[d] = (v[i] - mean) * rstd * sc[d] + bi[d];
  }
}

// ---------------------------------------------------------------- scatter x onto tri-planes (B,3,C,16,16)
__global__ __launch_bounds__(256) void scatter_kernel(const float* __restrict__ x,
                                                      const float* __restrict__ centers,
                                                      const float* __restrict__ Lv,
                                                      float* __restrict__ tri) {
  const int pnt = blockIdx.x;  // b*K + k
  const int b = pnt >> 10;
  const int tid = threadIdx.x;
  __shared__ int g[3];
  if (tid == 0) {
    float L = Lv[0];
    float half = __fmul_rn(L, 0.5f);
#pragma unroll
    for (int a = 0; a < 3; ++a) {
      float c = centers[(size_t)pnt * 3 + a];
      float t = __fmul_rn(__fdiv_rn(__fadd_rn(c, half), L), 16.f);
      int gi = (int)t;               // trunc toward zero, matches astype(int32)
      g[a] = min(15, max(0, gi));
    }
  }
  __syncthreads();
  const int gx = g[0], gy = g[1], gz = g[2];
  float v = x[(size_t)pnt * 256 + tid];
  float* trib = tri + (size_t)b * 3 * 256 * 256;
  atomicAdd(&trib[(0 * 256 + tid) * 256 + gy * 16 + gx], v);
  atomicAdd(&trib[(1 * 256 + tid) * 256 + gz * 16 + gy], v);
  atomicAdd(&trib[(2 * 256 + tid) * 256 + gz * 16 + gx], v);
}

// ---------------------------------------------------------------- direct conv 3x3 stride2 pad1 + bias + relu
template <int IC, int OC, int IH, int IW, int OH, int OW, int OCT, int ICC>
__global__ __launch_bounds__(256, 1) void conv_kernel(const float* __restrict__ in, const float* __restrict__ w,
                                                      const float* __restrict__ bias, float* __restrict__ out) {
  __shared__ float lin[ICC * IH * IW];
  const int n = blockIdx.x;
  const int oc = blockIdx.y * OCT + threadIdx.x / (OH * OW);
  const int sp = threadIdx.x % (OH * OW);
  const int oy = sp / OW, ox = sp % OW;
  const int iy0 = oy * 2 - 1, ix0 = ox * 2 - 1;
  float acc = 0.f;
  for (int c0 = 0; c0 < IC; c0 += ICC) {
    __syncthreads();
    for (int i = threadIdx.x; i < ICC * IH * IW; i += 256)
      lin[i] = in[((size_t)n * IC + c0) * (IH * IW) + i];
    __syncthreads();
    const float* wp = w + ((size_t)oc * IC + c0) * 9;
    for (int ic = 0; ic < ICC; ++ic) {
      const float* wr = wp + (size_t)ic * 9;
      const float* lr = lin + ic * IH * IW;
#pragma unroll
      for (int ky = 0; ky < 3; ++ky) {
        int iy = iy0 + ky;
        if (iy >= 0 && iy < IH) {
#pragma unroll
          for (int kx = 0; kx < 3; ++kx) {
            int ix = ix0 + kx;
            if (ix >= 0 && ix < IW) acc += lr[iy * IW + ix] * wr[ky * 3 + kx];
          }
        }
      }
    }
  }
  out[((size_t)n * OC + oc) * (OH * OW) + sp] = fmaxf(acc + bias[oc], 0.f);
}

// ---------------------------------------------------------------- conv3 weight-minimal: one block per 64-oc tile,
// all 12 planes inside (weights read exactly once: 75 MB total).
// IC=1024, OC=2048, IH=IW=4, OH=OW=2. LDS: 12 planes x 128-ic chunk x 16 spatial = 96 KB.
// Per-output accumulation order (c0 asc, ic asc, ky/kx) identical to conv_kernel -> bit-exact.
__global__ __launch_bounds__(256, 1) void conv3w_kernel(const float* __restrict__ in,
                                                        const float* __restrict__ w,
                                                        const float* __restrict__ bias,
                                                        float* __restrict__ out) {
  __shared__ float lin[12][128][16];
  const int oc = blockIdx.x * 64 + (threadIdx.x >> 2);
  const int sp = threadIdx.x & 3;
  const int oy = sp >> 1, ox = sp & 1;
  const int iy0 = oy * 2 - 1, ix0 = ox * 2 - 1;
  float acc[12] = {};
  for (int c0 = 0; c0 < 1024; c0 += 128) {
    __syncthreads();
    // stage 12 x 128 x 16 floats (6144 float4, 24 per thread, coalesced per plane)
    for (int i = threadIdx.x; i < 6144; i += 256) {
      int n = i / 512, r4 = i - n * 512;
      ((float4*)&lin[n][0][0])[r4] = ((const float4*)(in + ((size_t)n * 1024 + c0) * 16))[r4];
    }
    __syncthreads();
    const float* wp = w + ((size_t)oc * 1024 + c0) * 9;
    for (int ic = 0; ic < 128; ++ic) {
      const float* wr = wp + (size_t)ic * 9;
      float wv[9];
#pragma unroll
      for (int q = 0; q < 9; ++q) wv[q] = wr[q];
#pragma unroll
      for (int n = 0; n < 12; ++n) {
        const float* lr = &lin[n][ic][0];
        float a = acc[n];
#pragma unroll
        for (int ky = 0; ky < 3; ++ky) {
          int iy = iy0 + ky;
          if (iy >= 0 && iy < 4) {
#pragma unroll
            for (int kx = 0; kx < 3; ++kx) {
              int ix = ix0 + kx;
              if (ix >= 0 && ix < 4) a += lr[iy * 4 + ix] * wv[ky * 3 + kx];
            }
          }
        }
        acc[n] = a;
      }
    }
  }
  float bv = bias[oc];
#pragma unroll
  for (int n = 0; n < 12; ++n)
    out[((size_t)n * 2048 + oc) * 4 + sp] = fmaxf(acc[n] + bv, 0.f);
}

// ---------------------------------------------------------------- K-split matvec partials, float4 columns per thread
template <int M, int KC>
__global__ __launch_bounds__(256, 1) void matvec_part4_kernel(const float* __restrict__ A,
                                                              const float* __restrict__ W,
                                                              float* __restrict__ part,
                                                              int Kd, int Nd) {
  __shared__ float Al[KC * M];
  const int tid = threadIdx.x;
  const int n4 = blockIdx.x * 256 + tid;    // float4 column index
  const int nd4 = Nd >> 2;
  const int k0 = blockIdx.y * KC;
  for (int i = tid; i < KC * M; i += 256) {
    int k = i / M, m = i - k * M;
    Al[i] = A[(size_t)m * Kd + k0 + k];
  }
  __syncthreads();
  float4 acc[M];
#pragma unroll
  for (int m = 0; m < M; ++m) acc[m] = make_float4(0.f, 0.f, 0.f, 0.f);
  const float4* W4 = (const float4*)W;
  for (int k = 0; k < KC; ++k) {
    float4 wv = W4[(size_t)(k0 + k) * nd4 + n4];
#pragma unroll
    for (int m = 0; m < M; ++m) {
      float a = Al[k * M + m];
      acc[m].x += a * wv.x; acc[m].y += a * wv.y; acc[m].z += a * wv.z; acc[m].w += a * wv.w;
    }
  }
  float4* pp = (float4*)(part + ((size_t)blockIdx.y * M) * Nd);
#pragma unroll
  for (int m = 0; m < M; ++m) pp[(size_t)m * nd4 + n4] = acc[m];
}

// ---------------------------------------------------------------- sum 16 partials + bias -> out (M*Nd elements)
__global__ __launch_bounds__(256) void redsum_kernel(const float* __restrict__ part,
                                                     const float* __restrict__ bias,
                                                     float* __restrict__ out, int Nd, int total) {
  int i = blockIdx.x * 256 + threadIdx.x;
  if (i < total) {
    int n = i % Nd;
    float s = bias[n];
#pragma unroll
    for (int c = 0; c < 16; ++c) s += part[(size_t)c * total + i];
    out[i] = s;
  }
}

// ---------------------------------------------------------------- final attention: S=3, dh=1024, 8 heads
__global__ __launch_bounds__(256) void attn3_kernel(const float* __restrict__ qkv, float* __restrict__ o) {
  const int b = blockIdx.x >> 3, h = blockIdx.x & 7;
  const float* base = qkv + (size_t)b * 3 * N3E;
  const int qo = h * 1024, ko = EDIM + h * 1024, vo = 2 * EDIM + h * 1024;
  float p[9] = {};
  for (int d = threadIdx.x; d < 1024; d += 256) {
    float q0 = base[qo + d], q1 = base[N3E + qo + d], q2 = base[2 * N3E + qo + d];
    float k0 = base[ko + d], k1 = base[N3E + ko + d], k2 = base[2 * N3E + ko + d];
    p[0] += q0 * k0; p[1] += q0 * k1; p[2] += q0 * k2;
    p[3] += q1 * k0; p[4] += q1 * k1; p[5] += q1 * k2;
    p[6] += q2 * k0; p[7] += q2 * k1; p[8] += q2 * k2;
  }
  __shared__ float red[4][9];
  __shared__ float aw[9];
  const int lane = threadIdx.x & 63, w = threadIdx.x >> 6;
#pragma unroll
  for (int e = 0; e < 9; ++e)
#pragma unroll
    for (int off = 32; off >= 1; off >>= 1) p[e] += __shfl_xor(p[e], off, 64);
  if (lane == 0)
#pragma unroll
    for (int e = 0; e < 9; ++e) red[w][e] = p[e];
  __syncthreads();
  if (threadIdx.x == 0) {
    float s[9];
#pragma unroll
    for (int e = 0; e < 9; ++e) s[e] = (red[0][e] + red[1][e] + red[2][e] + red[3][e]) / 32.f; // /sqrt(1024)
#pragma unroll
    for (int i = 0; i < 3; ++i) {
      float m = fmaxf(fmaxf(s[i * 3], s[i * 3 + 1]), s[i * 3 + 2]);
      float e0 = expf(s[i * 3] - m), e1 = expf(s[i * 3 + 1] - m), e2 = expf(s[i * 3 + 2] - m);
      float sm = e0 + e1 + e2;
      aw[i * 3] = e0 / sm; aw[i * 3 + 1] = e1 / sm; aw[i * 3 + 2] = e2 / sm;
    }
  }
  __syncthreads();
  for (int d = threadIdx.x; d < 1024; d += 256) {
    float v0 = base[vo + d], v1 = base[N3E + vo + d], v2 = base[2 * N3E + vo + d];
#pragma unroll
    for (int i = 0; i < 3; ++i)
      o[(size_t)(b * 3 + i) * EDIM + h * 1024 + d] = aw[i * 3] * v0 + aw[i * 3 + 1] * v1 + aw[i * 3 + 2] * v2;
  }
}

// ================================================================ launch
extern "C" void kernel_launch(void* const* d_in, const int* in_sizes, int n_in,
                              void* d_out, int out_size, void* d_ws, size_t ws_size,
                              hipStream_t stream) {
  const float* pc      = (const float*)d_in[0];
  const float* pe_w1   = (const float*)d_in[1];
  const float* pe_b1   = (const float*)d_in[2];
  const float* pe_w2   = (const float*)d_in[3];
  const float* pe_b2   = (const float*)d_in[4];
  const float* t_qkv_w = (const float*)d_in[5];
  const float* t_qkv_b = (const float*)d_in[6];
  const float* t_out_w = (const float*)d_in[7];
  const float* t_out_b = (const float*)d_in[8];
  const float* t_ln1_s = (const float*)d_in[9];
  const float* t_ln1_b = (const float*)d_in[10];
  const float* t_ff1_w = (const float*)d_in[11];
  const float* t_ff1_b = (const float*)d_in[12];
  const float* t_ff2_w = (const float*)d_in[13];
  const float* t_ff2_b = (const float*)d_in[14];
  const float* t_ln2_s = (const float*)d_in[15];
  const float* t_ln2_b = (const float*)d_in[16];
  const float* c1_w    = (const float*)d_in[17];
  const float* c1_b    = (const float*)d_in[18];
  const float* c2_w    = (const float*)d_in[19];
  const float* c2_b    = (const float*)d_in[20];
  const float* c3_w    = (const float*)d_in[21];
  const float* c3_b    = (const float*)d_in[22];
  const float* x_qkv_w = (const float*)d_in[23];
  const float* x_qkv_b = (const float*)d_in[24];
  const float* x_out_w = (const float*)d_in[25];
  const float* x_out_b = (const float*)d_in[26];
  float* outp = (float*)d_out;

  // workspace layout (peak dominated by transformer arena; partials alias it)
  char* wsp = (char*)d_ws;
  auto alloc = [&](size_t bytes) { char* q = wsp; wsp += (bytes + 255) & ~(size_t)255; return q; };
  float* centers = (float*)alloc((size_t)NBATCH * KCP * 3 * 4);
  float* pmax    = (float*)alloc(512 * 4);
  float* pmin    = (float*)alloc(512 * 4);
  float* Lv      = (float*)alloc(256);
  unsigned* tags = (unsigned*)alloc((size_t)NBATCH * RING * 64 * 4);                          // 16 KB
  unsigned long long* keyss = (unsigned long long*)alloc((size_t)NBATCH * RING * 64 * GPUB * 8); // 256 KB (adjacent to tags)
  float* mindbuf = (float*)alloc((size_t)NBATCH * NPTS * 4);                                  // 1 MB
  int* fstate    = (int*)alloc(256);
  float* x  = (float*)alloc((size_t)4096 * 256 * 4);
  float* xb = (float*)alloc((size_t)4096 * 256 * 4);
  float* arena = (float*)wsp;
  // transformer views
  float* qkvb = arena;
  float* ao   = qkvb + (size_t)4096 * 768;
  float* po   = ao + (size_t)4096 * 256;
  float* ffh  = po + (size_t)4096 * 256;
  float* ffo  = ffh + (size_t)4096 * 1024;
  // post-phase views (alias arena; transformer scratch dead by then)
  float* tri  = arena;
  float* z1   = tri + (size_t)NBATCH * 3 * 256 * 256;
  float* z2   = z1 + (size_t)12 * 512 * 64;
  float* z3   = z2 + (size_t)12 * 1024 * 16;
  float* qkv2 = z3 + (size_t)12 * 8192;
  float* at2  = qkv2 + (size_t)12 * N3E;
  float* mvp  = at2 + (size_t)12 * EDIM;   // 16 x 12 x N3E partials (18.9 MB, < transformer arena)
  (void)in_sizes; (void)n_in; (void)out_size; (void)ws_size; (void)ffo;

  // FPS mailbox must be zero every call (tags poll vs round#; 0 = not ready).
  hipMemsetAsync(tags, 0, (size_t)NBATCH * RING * 64 * 4 + (size_t)NBATCH * RING * 64 * GPUB * 8, stream);

  redmm_kernel<<<512, 256, 0, stream>>>(pc, NBATCH * NPTS * 3, pmax, pmin);
  redfin_kernel<<<1, 256, 0, stream>>>(pmax, pmin, 512, Lv);

  fps_kernel<<<NBATCH * FPS_NBLK, FPS_THR, 0, stream>>>(pc, centers, tags, keyss, mindbuf, fstate, 0);
  fps_kernel<<<NBATCH * FPS_NBLK, FPS_THR, 0, stream>>>(pc, centers, tags, keyss, mindbuf, fstate, 1);

  pe_kernel<<<NBATCH * KCP, 128, 0, stream>>>(centers, pe_w1, pe_b1, pe_w2, pe_b2, x);

  for (int l = 0; l < 2; ++l) {
    gemm_mfma_kernel<<<dim3(6, 32), 256, 0, stream>>>(x, t_qkv_w + (size_t)l * 256 * 768,
                                                      t_qkv_b + (size_t)l * 768, qkvb, 4096, 256, 768, 0);
    flash_mfma_kernel<<<dim3(16, 8, 4), 256, 0, stream>>>(qkvb, ao);
    gemm_mfma_kernel<<<dim3(2, 32), 256, 0, stream>>>(ao, t_out_w + (size_t)l * 256 * 256,
                                                      t_out_b + (size_t)l * 256, po, 4096, 256, 256, 0);
    ln_kernel<<<1024, 256, 0, stream>>>(x, po, t_ln1_s + (size_t)l * 256, t_ln1_b + (size_t)l * 256, xb);
    gemm_mfma_kernel<<<dim3(8, 32), 256, 0, stream>>>(xb, t_ff1_w + (size_t)l * 256 * 1024,
                                                      t_ff1_b + (size_t)l * 1024, ffh, 4096, 256, 1024, 1);
    gemm_mfma_kernel<<<dim3(2, 32), 256, 0, stream>>>(ffh, t_ff2_w + (size_t)l * 1024 * 256,
                                                      t_ff2_b + (size_t)l * 256, ffo, 4096, 1024, 256, 0);
    ln_kernel<<<1024, 256, 0, stream>>>(xb, ffo, t_ln2_s + (size_t)l * 256, t_ln2_b + (size_t)l * 256, x);
  }

  // scatter to tri-planes (zero first: atomic accumulation, and arena was reused)
  hipMemsetAsync(tri, 0, (size_t)NBATCH * 3 * 256 * 256 * 4, stream);
  scatter_kernel<<<NBATCH * KCP, 256, 0, stream>>>(x, centers, Lv, tri);

  conv_kernel<256, 512, 16, 16, 8, 8, 4, 32><<<dim3(12, 128), 256, 0, stream>>>(tri, c1_w, c1_b, z1);
  conv_kernel<512, 1024, 8, 8, 4, 4, 16, 128><<<dim3(12, 64), 256, 0, stream>>>(z1, c2_w, c2_b, z2);
  conv3w_kernel<<<32, 256, 0, stream>>>(z2, c3_w, c3_b, z3);

  // qkv2 = z3 @ x_qkv_w + b : K-split float4 partials (no atomics) + fused reduce
  matvec_part4_kernel<12, 512><<<dim3(N3E / 1024, 16), 256, 0, stream>>>(z3, x_qkv_w, mvp, EDIM, N3E);
  redsum_kernel<<<(12 * N3E + 255) / 256, 256, 0, stream>>>(mvp, x_qkv_b, qkv2, N3E, 12 * N3E);

  attn3_kernel<<<32, 256, 0, stream>>>(qkv2, at2);

  matvec_part4_kernel<12, 512><<<dim3(EDIM / 1024, 16), 256, 0, stream>>>(at2, x_out_w, mvp, EDIM, EDIM);
  redsum_kernel<<<(12 * EDIM + 255) / 256, 256, 0, stream>>>(mvp, x_out_b, outp, EDIM, 12 * EDIM);
}

// Round 16
// 4356.842 us; speedup vs baseline: 1.5139x; 1.5139x over previous
//
#include <hip/hip_runtime.h>
#include <math.h>

// Problem constants
#define NPTS   65536
#define NBATCH 4
#define KCP    1024      // NCP centers
#define DM     256
#define FFD    1024
#define EDIM   8192      // E
#define N3E    24576     // 3*E

// FPS decomposition: 16 blocks/batch x 256 threads (4 waves); 64 publisher-waves
// per batch, each wave owns 1024 points (16/thread) held in registers.
#define FPS_NBLK 16
#define FPS_THR  256
#define FPS_PPT  16
#define GPUB     8       // keys published per wave per round (last one = bound) [empirical optimum]
#define HARV_MAX 16      // max winners harvested per global sync round
#define RING     16      // mailbox ring depth (rounds)
#define TSPLIT   512     // phase-0/phase-1 split point (2-dispatch fps)

typedef __attribute__((ext_vector_type(8))) short short8v;
typedef __attribute__((ext_vector_type(4))) short short4v;
typedef __attribute__((ext_vector_type(4))) float float4v;

__device__ __forceinline__ unsigned long long umaxll(unsigned long long a, unsigned long long b) {
  return a > b ? a : b;
}

__device__ __forceinline__ short bf16rn(float f) {
  unsigned u = __float_as_uint(f);
  return (short)((u + 0x7FFFu + ((u >> 16) & 1u)) >> 16);
}

// ---------------------------------------------------------------- global min/max (for L)
__global__ __launch_bounds__(256) void redmm_kernel(const float* __restrict__ v, int n,
                                                    float* __restrict__ pmax, float* __restrict__ pmin) {
  float mx = -INFINITY, mn = INFINITY;
  for (int i = blockIdx.x * 256 + threadIdx.x; i < n; i += gridDim.x * 256) {
    float x = v[i]; mx = fmaxf(mx, x); mn = fminf(mn, x);
  }
#pragma unroll
  for (int off = 32; off >= 1; off >>= 1) {
    mx = fmaxf(mx, __shfl_xor(mx, off, 64));
    mn = fminf(mn, __shfl_xor(mn, off, 64));
  }
  __shared__ float smx[4], smn[4];
  int lane = threadIdx.x & 63, w = threadIdx.x >> 6;
  if (lane == 0) { smx[w] = mx; smn[w] = mn; }
  __syncthreads();
  if (threadIdx.x == 0) {
    pmax[blockIdx.x] = fmaxf(fmaxf(smx[0], smx[1]), fmaxf(smx[2], smx[3]));
    pmin[blockIdx.x] = fminf(fminf(smn[0], smn[1]), fminf(smn[2], smn[3]));
  }
}

__global__ __launch_bounds__(256) void redfin_kernel(const float* __restrict__ pmax,
                                                     const float* __restrict__ pmin, int nb,
                                                     float* __restrict__ Lv) {
  float mx = -INFINITY, mn = INFINITY;
  for (int i = threadIdx.x; i < nb; i += 256) { mx = fmaxf(mx, pmax[i]); mn = fminf(mn, pmin[i]); }
#pragma unroll
  for (int off = 32; off >= 1; off >>= 1) {
    mx = fmaxf(mx, __shfl_xor(mx, off, 64));
    mn = fminf(mn, __shfl_xor(mn, off, 64));
  }
  __shared__ float smx[4], smn[4];
  int lane = threadIdx.x & 63, w = threadIdx.x >> 6;
  if (lane == 0) { smx[w] = mx; smn[w] = mn; }
  __syncthreads();
  if (threadIdx.x == 0) {
    mx = fmaxf(fmaxf(smx[0], smx[1]), fmaxf(smx[2], smx[3]));
    mn = fminf(fminf(smn[0], smn[1]), fminf(smn[2], smn[3]));
    Lv[0] = __fsub_rn(mx, mn);
  }
}

// ---------------------------------------------------------------- FPS: top-8 harvesting, single-poller-per-block
__global__ __launch_bounds__(FPS_THR, 1) void fps_kernel(const float* __restrict__ pc,
                                                         float* __restrict__ centers,
                                                         unsigned* __restrict__ tags,
                                                         unsigned long long* __restrict__ keys,
                                                         float* __restrict__ mindbuf,
                                                         int* __restrict__ state,
                                                         int phase) {
  const int blk = blockIdx.x;
  const int b = blk / FPS_NBLK, bb = blk % FPS_NBLK;
  const int tid = threadIdx.x;
  const int lane = tid & 63, wv = tid >> 6;
  const int wvg = bb * 4 + wv;                 // wave id in batch: 0..63
  const float* pcb = pc + (size_t)b * NPTS * 3;

  __shared__ float kpts[96];
  __shared__ float wlds[2][HARV_MAX][3];
  __shared__ int hcnt[2];

  float px[FPS_PPT], py[FPS_PPT], pz[FPS_PPT], mind[FPS_PPT];
  const int gbase = wvg * 1024;                // 1024 points per wave
#pragma unroll
  for (int i = 0; i < FPS_PPT; ++i) {
    int g = gbase + i * 64 + lane;
    px[i] = pcb[3 * g]; py[i] = pcb[3 * g + 1]; pz[i] = pcb[3 * g + 2];
  }

  unsigned* const tagb = tags + (size_t)b * RING * 64;                   // [RING][64] u32
  unsigned long long* const keyb = keys + (size_t)b * RING * 64 * GPUB;  // [RING][64][GPUB]
  float* const mb = mindbuf + ((size_t)b * 64 + wvg) * FPS_PPT * 64;

  int t, r;
  if (phase == 0) {
    for (int i = tid; i < 96; i += FPS_THR) kpts[i] = pcb[i];
    __syncthreads();   // kpts ready
    // --- round 1: density over first 32 points (IEEE f32, op-for-op) -> center 0
    unsigned long long bk = 0ull;
#pragma unroll
    for (int i = 0; i < FPS_PPT; ++i) {
      float acc = 0.f;
      for (int j = 0; j < 32; ++j) {
        float dx = __fsub_rn(px[i], kpts[3 * j]);
        float dy = __fsub_rn(py[i], kpts[3 * j + 1]);
        float dz = __fsub_rn(pz[i], kpts[3 * j + 2]);
        float ss = __fadd_rn(__fadd_rn(__fmul_rn(dx, dx), __fmul_rn(dy, dy)), __fmul_rn(dz, dz));
        float d = __fsqrt_rn(ss);
        float dd = __fadd_rn(__fmul_rn(d, d), 1e-6f);
        acc = __fadd_rn(acc, expf(__fdiv_rn(-0.02f, dd)));
      }
      float dens = __fdiv_rn(acc, 32.f);
      int g = gbase + i * 64 + lane;
      bk = umaxll(bk, ((unsigned long long)__float_as_uint(dens) << 32) | (unsigned int)(~g));
    }
#pragma unroll
    for (int off = 1; off < 64; off <<= 1) bk = umaxll(bk, __shfl_xor(bk, off, 64));
    if (lane == 0) {
      keyb[(size_t)(1 & (RING - 1)) * 64 * GPUB + wvg * GPUB] = bk;
      __hip_atomic_store(&tagb[(1 & (RING - 1)) * 64 + wvg], 1u, __ATOMIC_RELEASE, __HIP_MEMORY_SCOPE_AGENT);
    }
    unsigned tag;
    do {
      tag = __hip_atomic_load(&tagb[(1 & (RING - 1)) * 64 + lane], __ATOMIC_ACQUIRE, __HIP_MEMORY_SCOPE_AGENT);
    } while (__any(tag != 1u));
    unsigned long long k2 = __hip_atomic_load(&keyb[(size_t)(1 & (RING - 1)) * 64 * GPUB + lane * GPUB],
                                              __ATOMIC_RELAXED, __HIP_MEMORY_SCOPE_AGENT);
#pragma unroll
    for (int off = 1; off < 64; off <<= 1) k2 = umaxll(k2, __shfl_xor(k2, off, 64));
    int widx = (int)(~(unsigned)(k2 & 0xFFFFFFFFull));
    float wx = pcb[3 * widx], wy = pcb[3 * widx + 1], wz = pcb[3 * widx + 2];
    if (wvg == 0 && lane == 0) {
      centers[(size_t)b * KCP * 3 + 0] = wx;
      centers[(size_t)b * KCP * 3 + 1] = wy;
      centers[(size_t)b * KCP * 3 + 2] = wz;
    }
#pragma unroll
    for (int i = 0; i < FPS_PPT; ++i) {
      float dx = __fsub_rn(px[i], wx), dy = __fsub_rn(py[i], wy), dz = __fsub_rn(pz[i], wz);
      mind[i] = __fsqrt_rn(__fadd_rn(__fadd_rn(__fmul_rn(dx, dx), __fmul_rn(dy, dy)), __fmul_rn(dz, dz)));
    }
    t = 1; r = 2;
  } else {
    r = state[b * 2]; t = state[b * 2 + 1];
#pragma unroll
    for (int i = 0; i < FPS_PPT; ++i) mind[i] = mb[i * 64 + lane];
  }

  const int tend = phase ? KCP : TSPLIT;
  while (t < tend) {
    // every wave: fresh keys + extract top-8 (keys only)
    unsigned long long tk[FPS_PPT];
#pragma unroll
    for (int i = 0; i < FPS_PPT; ++i) {
      int g = gbase + i * 64 + lane;
      tk[i] = ((unsigned long long)__float_as_uint(mind[i]) << 32) | (unsigned int)(~g);
    }
    unsigned long long ek[GPUB];
#pragma unroll
    for (int g = 0; g < GPUB; ++g) {
      unsigned long long lbk = 0ull;
#pragma unroll
      for (int i = 0; i < FPS_PPT; ++i) lbk = umaxll(lbk, tk[i]);
      unsigned long long wk = lbk;
#pragma unroll
      for (int off = 1; off < 64; off <<= 1) wk = umaxll(wk, __shfl_xor(wk, off, 64));
      ek[g] = wk;
#pragma unroll
      for (int i = 0; i < FPS_PPT; ++i)
        if (tk[i] == wk) tk[i] = 0ull;
    }
    const int ri = r & (RING - 1);
    if (lane == 0) {
      unsigned long long* sp = keyb + ((size_t)ri * 64 + wvg) * GPUB;
#pragma unroll
      for (int g = 0; g < GPUB; ++g)
        __hip_atomic_store(&sp[g], ek[g], __ATOMIC_RELAXED, __HIP_MEMORY_SCOPE_AGENT);
      __hip_atomic_store(&tagb[ri * 64 + wvg], (unsigned)r, __ATOMIC_RELEASE, __HIP_MEMORY_SCOPE_AGENT);
    }

    if (wv == 0) {
      // single poller: wave 0 of each block
      unsigned tag;
      do {
        tag = __hip_atomic_load(&tagb[ri * 64 + lane], __ATOMIC_ACQUIRE, __HIP_MEMORY_SCOPE_AGENT);
      } while (__any(tag != (unsigned)r));
      const unsigned long long* pl = keyb + ((size_t)ri * 64 + lane) * GPUB;
      unsigned long long ck[GPUB];
#pragma unroll
      for (int e = 0; e < GPUB; ++e)
        ck[e] = __hip_atomic_load(&pl[e], __ATOMIC_RELAXED, __HIP_MEMORY_SCOPE_AGENT);
      float cx[GPUB], cy[GPUB], cz[GPUB];
#pragma unroll
      for (int e = 0; e < GPUB; ++e) {
        int gi = (int)(~(unsigned)(ck[e] & 0xFFFFFFFFull));
        cx[e] = pcb[3 * gi]; cy[e] = pcb[3 * gi + 1]; cz[e] = pcb[3 * gi + 2];
      }
      unsigned long long u = ck[GPUB - 1];
#pragma unroll
      for (int off = 1; off < 64; off <<= 1) u = umaxll(u, __shfl_xor(u, off, 64));
      int h = 0, tl = t;
      while (true) {
        unsigned long long lb = 0ull; float lx = 0.f, ly = 0.f, lz = 0.f;
#pragma unroll
        for (int e = 0; e < GPUB; ++e)
          if (ck[e] > lb) { lb = ck[e]; lx = cx[e]; ly = cy[e]; lz = cz[e]; }
        unsigned long long wk = lb;
#pragma unroll
        for (int off = 1; off < 64; off <<= 1) wk = umaxll(wk, __shfl_xor(wk, off, 64));
        if (h > 0 && wk < u) break;   // h==0 pick is always the true global argmax
        int owner = __ffsll(__ballot(lb == wk)) - 1;
        float wx = __shfl(lx, owner, 64), wy = __shfl(ly, owner, 64), wz = __shfl(lz, owner, 64);
        if (lane == 0) {
          wlds[r & 1][h][0] = wx; wlds[r & 1][h][1] = wy; wlds[r & 1][h][2] = wz;
          if (bb == 0) {
            centers[((size_t)b * KCP + tl) * 3 + 0] = wx;
            centers[((size_t)b * KCP + tl) * 3 + 1] = wy;
            centers[((size_t)b * KCP + tl) * 3 + 2] = wz;
          }
        }
#pragma unroll
        for (int e = 0; e < GPUB; ++e) {
          float dx = __fsub_rn(cx[e], wx), dy = __fsub_rn(cy[e], wy), dz = __fsub_rn(cz[e], wz);
          float d = __fsqrt_rn(__fadd_rn(__fadd_rn(__fmul_rn(dx, dx), __fmul_rn(dy, dy)), __fmul_rn(dz, dz)));
          float ov = __uint_as_float((unsigned)(ck[e] >> 32));
          float nv = fminf(ov, d);
          ck[e] = ((unsigned long long)__float_as_uint(nv) << 32) | (ck[e] & 0xFFFFFFFFull);
        }
        ++h; ++tl;
        if (h == HARV_MAX || tl == KCP) break;
      }
      if (lane == 0) hcnt[r & 1] = h;
    }
    __syncthreads();
    const int h = hcnt[r & 1];
    for (int j = 0; j < h; ++j) {
      float wx = wlds[r & 1][j][0], wy = wlds[r & 1][j][1], wz = wlds[r & 1][j][2];
#pragma unroll
      for (int i = 0; i < FPS_PPT; ++i) {
        float dx = __fsub_rn(px[i], wx), dy = __fsub_rn(py[i], wy), dz = __fsub_rn(pz[i], wz);
        float d = __fsqrt_rn(__fadd_rn(__fadd_rn(__fmul_rn(dx, dx), __fmul_rn(dy, dy)), __fmul_rn(dz, dz)));
        mind[i] = fminf(mind[i], d);
      }
    }
    t += h; ++r;
  }

  if (phase == 0) {
#pragma unroll
    for (int i = 0; i < FPS_PPT; ++i) mb[i * 64 + lane] = mind[i];
    if (bb == 0 && wv == 0 && lane == 0) { state[b * 2] = r; state[b * 2 + 1] = t; }
  }
}

// ---------------------------------------------------------------- point encoder + pos-emb -> x (B,K,256)
__global__ __launch_bounds__(128) void pe_kernel(const float* __restrict__ centers,
                                                 const float* __restrict__ w1, const float* __restrict__ b1,
                                                 const float* __restrict__ w2, const float* __restrict__ b2,
                                                 float* __restrict__ x) {
  const int p = blockIdx.x;      // b*K + k
  const int d = threadIdx.x;     // 0..127
  __shared__ float h[128];
  __shared__ float c[3];
  if (d < 3) c[d] = centers[(size_t)p * 3 + d];
  __syncthreads();
  float hv = b1[d];
#pragma unroll
  for (int j = 0; j < 3; ++j) hv += c[j] * w1[j * 128 + d];
  hv = fmaxf(hv, 0.f);
  h[d] = hv;
  __syncthreads();
  float f = b2[d];
  for (int j = 0; j < 128; ++j) f += h[j] * w2[j * 128 + d];
  x[(size_t)p * 256 + d] = f;
  if (d < 64) {
    float fr = expf(__fmul_rn((float)d, -0.14619587892025696f)); // -ln(10000)/63
    float ssum = 0.f, csum = 0.f;
#pragma unroll
    for (int a = 0; a < 3; ++a) {
      float e = __fmul_rn(c[a], fr);
      ssum += sinf(e); csum += cosf(e);
    }
    x[(size_t)p * 256 + 128 + d] = __fdiv_rn(ssum, 3.f);
    x[(size_t)p * 256 + 192 + d] = __fdiv_rn(csum, 3.f);
  }
}

// ---------------------------------------------------------------- bf16 MFMA GEMM: C = A(M,K)@W(K,N)+bias [relu]
__global__ __launch_bounds__(256) void gemm_mfma_kernel(const float* __restrict__ A,
                                                        const float* __restrict__ W,
                                                        const float* __restrict__ bias,
                                                        float* __restrict__ C,
                                                        int M, int Kd, int Nd, int relu) {
  __shared__ __align__(16) short Al[128][40];
  __shared__ __align__(16) short Wl[128][40];
  const int bm = blockIdx.y * 128, bn = blockIdx.x * 128;
  const int tid = threadIdx.x;
  const int lane = tid & 63, wv = tid >> 6;
  const int wr = wv >> 1, wc = wv & 1;
  const int l15 = lane & 15, lk = lane >> 4;

  float4v acc[4][4];
#pragma unroll
  for (int i = 0; i < 4; ++i)
#pragma unroll
    for (int j = 0; j < 4; ++j) acc[i][j] = (float4v){0.f, 0.f, 0.f, 0.f};

  for (int k0 = 0; k0 < Kd; k0 += 32) {
    __syncthreads();
#pragma unroll
    for (int i = 0; i < 4; ++i) {
      int idx = (i * 256 + tid) * 4;        // 0..4095
      int m = idx >> 5, k = idx & 31;
      float4 v = *(const float4*)&A[(size_t)(bm + m) * Kd + k0 + k];
      short4v s = { bf16rn(v.x), bf16rn(v.y), bf16rn(v.z), bf16rn(v.w) };
      *(short4v*)&Al[m][k] = s;
    }
#pragma unroll
    for (int i = 0; i < 4; ++i) {
      int task = i * 256 + tid;
      int n = task & 127, c = task >> 7;
      short4v s;
#pragma unroll
      for (int j = 0; j < 4; ++j)
        s[j] = bf16rn(W[(size_t)(k0 + c * 4 + j) * Nd + bn + n]);
      *(short4v*)&Wl[n][c * 4] = s;
    }
    __syncthreads();
    short8v af[4], bf[4];
#pragma unroll
    for (int mf = 0; mf < 4; ++mf)
      af[mf] = *(const short8v*)&Al[wr * 64 + mf * 16 + l15][lk * 8];
#pragma unroll
    for (int nf = 0; nf < 4; ++nf)
      bf[nf] = *(const short8v*)&Wl[wc * 64 + nf * 16 + l15][lk * 8];
#pragma unroll
    for (int mf = 0; mf < 4; ++mf)
#pragma unroll
      for (int nf = 0; nf < 4; ++nf)
        acc[mf][nf] = __builtin_amdgcn_mfma_f32_16x16x32_bf16(af[mf], bf[nf], acc[mf][nf], 0, 0, 0);
  }

#pragma unroll
  for (int mf = 0; mf < 4; ++mf) {
    int row = bm + wr * 64 + mf * 16 + lk * 4;
#pragma unroll
    for (int nf = 0; nf < 4; ++nf) {
      int col = bn + wc * 64 + nf * 16 + l15;
      float bv = bias[col];
#pragma unroll
      for (int j = 0; j < 4; ++j) {
        float v = acc[mf][nf][j] + bv;
        if (relu) v = fmaxf(v, 0.f);
        C[(size_t)(row + j) * Nd + col] = v;
      }
    }
  }
}

// ---------------------------------------------------------------- MFMA flash attention (S=1024, dh=32, nh=8)
__global__ __launch_bounds__(256, 1) void flash_mfma_kernel(const float* __restrict__ qkv,
                                                            float* __restrict__ ao) {
  const int qt = blockIdx.x, h = blockIdx.y, b = blockIdx.z;
  const int tid = threadIdx.x;
  const int lane = tid & 63, w = tid >> 6;
  const int l15 = lane & 15, lk = lane >> 4;
  const int q0 = qt * 64;

  __shared__ __align__(16) short Kc[64][40];    // [key][dim]
  __shared__ __align__(16) short Vt[32][72];    // [dim][key] (transposed)
  __shared__ __align__(16) short Plds[4][16][72]; // per-wave [q][key]

  short8v qa;
  {
    const float* qr = qkv + (size_t)(b * 1024 + q0 + w * 16 + l15) * 768 + h * 32 + lk * 8;
    float4 a = *(const float4*)qr;
    float4 c = *(const float4*)(qr + 4);
    qa = (short8v){ bf16rn(a.x), bf16rn(a.y), bf16rn(a.z), bf16rn(a.w),
                    bf16rn(c.x), bf16rn(c.y), bf16rn(c.z), bf16rn(c.w) };
  }

  float4v o0 = (float4v){0.f, 0.f, 0.f, 0.f};
  float4v o1 = (float4v){0.f, 0.f, 0.f, 0.f};
  float m_cur[4] = { -INFINITY, -INFINITY, -INFINITY, -INFINITY };
  float l_part[4] = { 0.f, 0.f, 0.f, 0.f };
  const float scale = 0.17677669529663687f;   // 1/sqrt(32)

  for (int c0 = 0; c0 < 1024; c0 += 64) {
    __syncthreads();
    {
      int key = tid >> 2, dblk = (tid & 3) * 8;
      size_t row = (size_t)(b * 1024 + c0 + key) * 768 + h * 32 + dblk;
      float4 k1 = *(const float4*)&qkv[row + 256];
      float4 k2 = *(const float4*)&qkv[row + 260];
      short8v ks = (short8v){ bf16rn(k1.x), bf16rn(k1.y), bf16rn(k1.z), bf16rn(k1.w),
                              bf16rn(k2.x), bf16rn(k2.y), bf16rn(k2.z), bf16rn(k2.w) };
      *(short8v*)&Kc[key][dblk] = ks;
      float4 v1 = *(const float4*)&qkv[row + 512];
      float4 v2 = *(const float4*)&qkv[row + 516];
      Vt[dblk + 0][key] = bf16rn(v1.x); Vt[dblk + 1][key] = bf16rn(v1.y);
      Vt[dblk + 2][key] = bf16rn(v1.z); Vt[dblk + 3][key] = bf16rn(v1.w);
      Vt[dblk + 4][key] = bf16rn(v2.x); Vt[dblk + 5][key] = bf16rn(v2.y);
      Vt[dblk + 6][key] = bf16rn(v2.z); Vt[dblk + 7][key] = bf16rn(v2.w);
    }
    __syncthreads();

    float4v s[4];
#pragma unroll
    for (int f = 0; f < 4; ++f) {
      short8v kb = *(const short8v*)&Kc[f * 16 + l15][lk * 8];
      float4v z = (float4v){0.f, 0.f, 0.f, 0.f};
      s[f] = __builtin_amdgcn_mfma_f32_16x16x32_bf16(qa, kb, z, 0, 0, 0);
    }
#pragma unroll
    for (int f = 0; f < 4; ++f)
#pragma unroll
      for (int j = 0; j < 4; ++j) s[f][j] *= scale;

    float corr[4];
#pragma unroll
    for (int j = 0; j < 4; ++j) {
      float v = fmaxf(fmaxf(s[0][j], s[1][j]), fmaxf(s[2][j], s[3][j]));
#pragma unroll
      for (int off = 1; off < 16; off <<= 1) v = fmaxf(v, __shfl_xor(v, off, 64));
      float m_new = fmaxf(m_cur[j], v);
      corr[j] = expf(m_cur[j] - m_new);
      m_cur[j] = m_new;
    }
#pragma unroll
    for (int f = 0; f < 4; ++f)
#pragma unroll
      for (int j = 0; j < 4; ++j) {
        float p = expf(s[f][j] - m_cur[j]);
        s[f][j] = p;
        Plds[w][lk * 4 + j][f * 16 + l15] = bf16rn(p);
      }
#pragma unroll
    for (int j = 0; j < 4; ++j) {
      float tsum = s[0][j] + s[1][j] + s[2][j] + s[3][j];
#pragma unroll
      for (int off = 1; off < 16; off <<= 1) tsum += __shfl_xor(tsum, off, 64);
      l_part[j] = l_part[j] * corr[j] + tsum;
      o0[j] *= corr[j];
      o1[j] *= corr[j];
    }
    asm volatile("s_waitcnt lgkmcnt(0)" ::: "memory");
    __builtin_amdgcn_sched_barrier(0);

#pragma unroll
    for (int kb = 0; kb < 2; ++kb) {
      short8v pa = *(const short8v*)&Plds[w][l15][kb * 32 + lk * 8];
      short8v vb0 = *(const short8v*)&Vt[l15][kb * 32 + lk * 8];
      short8v vb1 = *(const short8v*)&Vt[16 + l15][kb * 32 + lk * 8];
      o0 = __builtin_amdgcn_mfma_f32_16x16x32_bf16(pa, vb0, o0, 0, 0, 0);
      o1 = __builtin_amdgcn_mfma_f32_16x16x32_bf16(pa, vb1, o1, 0, 0, 0);
    }
  }

#pragma unroll
  for (int j = 0; j < 4; ++j) {
    float inv = 1.f / l_part[j];
    int q = q0 + w * 16 + lk * 4 + j;
    float* orow = ao + (size_t)(b * 1024 + q) * 256 + h * 32;
    orow[l15] = o0[j] * inv;
    orow[16 + l15] = o1[j] * inv;
  }
}

// ---------------------------------------------------------------- fused residual + LayerNorm (rows of 256)
__global__ __launch_bounds__(256) void ln_kernel(const float* __restrict__ a, const float* __restrict__ r,
                                                 const float* __restrict__ sc, const float* __restrict__ bi,
                                                 float* __restrict__ out) {
  const int row = blockIdx.x * 4 + (threadIdx.x >> 6);
  const int lane = threadIdx.x & 63;
  const float* ar = a + (size_t)row * 256;
  const float* rr = r + (size_t)row * 256;
  float v[4];
#pragma unroll
  for (int i = 0; i < 4; ++i) v[i] = ar[lane + 64 * i] + rr[lane + 64 * i];
  float s = v[0] + v[1] + v[2] + v[3];
#pragma unroll
  for (int off = 32; off >= 1; off >>= 1) s += __shfl_xor(s, off, 64);
  float mean = s * (1.f / 256.f);
  float vs = 0.f;
#pragma unroll
  for (int i = 0; i < 4; ++i) { float d = v[i] - mean; vs += d * d; }
#pragma unroll
  for (int off = 32; off >= 1; off >>= 1) vs += __shfl_xor(vs, off, 64);
  float var = vs * (1.f / 256.f);
  float rstd = 1.f / sqrtf(var + 1e-5f);
  float* orow = out + (size_t)row * 256;
#pragma unroll
  for (int i = 0; i < 4; ++i) {
    int d = lane + 64 * i;
    orow[d] = (v[i] - mean) * rstd * sc[d] + bi[d];
  }
}

// ---------------------------------------------------------------- scatter x onto tri-planes (B,3,C,16,16)
__global__ __launch_bounds__(256) void scatter_kernel(const float* __restrict__ x,
                                                      const float* __restrict__ centers,
                                                      const float* __restrict__ Lv,
                                                      float* __restrict__ tri) {
  const int pnt = blockIdx.x;  // b*K + k
  const int b = pnt >> 10;
  const int tid = threadIdx.x;
  __shared__ int g[3];
  if (tid == 0) {
    float L = Lv[0];
    float half = __fmul_rn(L, 0.5f);
#pragma unroll
    for (int a = 0; a < 3; ++a) {
      float c = centers[(size_t)pnt * 3 + a];
      float t = __fmul_rn(__fdiv_rn(__fadd_rn(c, half), L), 16.f);
      int gi = (int)t;               // trunc toward zero, matches astype(int32)
      g[a] = min(15, max(0, gi));
    }
  }
  __syncthreads();
  const int gx = g[0], gy = g[1], gz = g[2];
  float v = x[(size_t)pnt * 256 + tid];
  float* trib = tri + (size_t)b * 3 * 256 * 256;
  atomicAdd(&trib[(0 * 256 + tid) * 256 + gy * 16 + gx], v);
  atomicAdd(&trib[(1 * 256 + tid) * 256 + gz * 16 + gy], v);
  atomicAdd(&trib[(2 * 256 + tid) * 256 + gz * 16 + gx], v);
}

// ---------------------------------------------------------------- direct conv 3x3 stride2 pad1 + bias + relu
template <int IC, int OC, int IH, int IW, int OH, int OW, int OCT, int ICC>
__global__ __launch_bounds__(256, 1) void conv_kernel(const float* __restrict__ in, const float* __restrict__ w,
                                                      const float* __restrict__ bias, float* __restrict__ out) {
  __shared__ float lin[ICC * IH * IW];
  const int n = blockIdx.x;
  const int oc = blockIdx.y * OCT + threadIdx.x / (OH * OW);
  const int sp = threadIdx.x % (OH * OW);
  const int oy = sp / OW, ox = sp % OW;
  const int iy0 = oy * 2 - 1, ix0 = ox * 2 - 1;
  float acc = 0.f;
  for (int c0 = 0; c0 < IC; c0 += ICC) {
    __syncthreads();
    for (int i = threadIdx.x; i < ICC * IH * IW; i += 256)
      lin[i] = in[((size_t)n * IC + c0) * (IH * IW) + i];
    __syncthreads();
    const float* wp = w + ((size_t)oc * IC + c0) * 9;
    for (int ic = 0; ic < ICC; ++ic) {
      const float* wr = wp + (size_t)ic * 9;
      const float* lr = lin + ic * IH * IW;
#pragma unroll
      for (int ky = 0; ky < 3; ++ky) {
        int iy = iy0 + ky;
        if (iy >= 0 && iy < IH) {
#pragma unroll
          for (int kx = 0; kx < 3; ++kx) {
            int ix = ix0 + kx;
            if (ix >= 0 && ix < IW) acc += lr[iy * IW + ix] * wr[ky * 3 + kx];
          }
        }
      }
    }
  }
  out[((size_t)n * OC + oc) * (OH * OW) + sp] = fmaxf(acc + bias[oc], 0.f);
}

// ---------------------------------------------------------------- conv3 weights-once + full occupancy:
// one block per oc (2048 blocks). Stage w[oc] (36 KB) coalesced into LDS;
// threads 0..191 own (n,sp,ic-chunk-of-256), inputs (786 KB) come from L2.
// Reduce 4 chunk-partials in fixed order; + bias + relu.
__global__ __launch_bounds__(256, 1) void conv3g_kernel(const float* __restrict__ in,
                                                        const float* __restrict__ w,
                                                        const float* __restrict__ bias,
                                                        float* __restrict__ out) {
  __shared__ float wl[9216];
  __shared__ float psum[48][4];
  const int oc = blockIdx.x;
  const int tid = threadIdx.x;
  const float4* w4 = (const float4*)(w + (size_t)oc * 9216);
  for (int i = tid; i < 2304; i += 256)
    ((float4*)wl)[i] = w4[i];
  __syncthreads();
  if (tid < 192) {
    const int o = tid % 48, c = tid / 48;
    const int n = o >> 2, sp = o & 3;
    const int oy = sp >> 1, ox = sp & 1;
    const int iy0 = oy * 2 - 1, ix0 = ox * 2 - 1;
    float acc = 0.f;
    const float* inb = in + ((size_t)n * 1024 + c * 256) * 16;
    const float* wb = wl + c * 256 * 9;
    for (int ic = 0; ic < 256; ++ic) {
      const float* lr = inb + ic * 16;
      const float* wr = wb + ic * 9;
#pragma unroll
      for (int ky = 0; ky < 3; ++ky) {
        int iy = iy0 + ky;
        if (iy >= 0 && iy < 4) {
#pragma unroll
          for (int kx = 0; kx < 3; ++kx) {
            int ix = ix0 + kx;
            if (ix >= 0 && ix < 4) acc += lr[iy * 4 + ix] * wr[ky * 3 + kx];
          }
        }
      }
    }
    psum[o][c] = acc;
  }
  __syncthreads();
  if (tid < 48) {
    float s = ((psum[tid][0] + psum[tid][1]) + psum[tid][2]) + psum[tid][3];
    int n = tid >> 2, sp = tid & 3;
    out[((size_t)n * 2048 + oc) * 4 + sp] = fmaxf(s + bias[oc], 0.f);
  }
}

// ---------------------------------------------------------------- K-split matvec partials, float4 columns per thread
template <int M, int KC>
__global__ __launch_bounds__(256, 1) void matvec_part4_kernel(const float* __restrict__ A,
                                                              const float* __restrict__ W,
                                                              float* __restrict__ part,
                                                              int Kd, int Nd) {
  __shared__ float Al[KC * M];
  const int tid = threadIdx.x;
  const int n4 = blockIdx.x * 256 + tid;    // float4 column index
  const int nd4 = Nd >> 2;
  const int k0 = blockIdx.y * KC;
  for (int i = tid; i < KC * M; i += 256) {
    int k = i / M, m = i - k * M;
    Al[i] = A[(size_t)m * Kd + k0 + k];
  }
  __syncthreads();
  float4 acc[M];
#pragma unroll
  for (int m = 0; m < M; ++m) acc[m] = make_float4(0.f, 0.f, 0.f, 0.f);
  const float4* W4 = (const float4*)W;
  for (int k = 0; k < KC; ++k) {
    float4 wv = W4[(size_t)(k0 + k) * nd4 + n4];
#pragma unroll
    for (int m = 0; m < M; ++m) {
      float a = Al[k * M + m];
      acc[m].x += a * wv.x; acc[m].y += a * wv.y; acc[m].z += a * wv.z; acc[m].w += a * wv.w;
    }
  }
  float4* pp = (float4*)(part + ((size_t)blockIdx.y * M) * Nd);
#pragma unroll
  for (int m = 0; m < M; ++m) pp[(size_t)m * nd4 + n4] = acc[m];
}

// ---------------------------------------------------------------- sum 16 partials + bias -> out (M*Nd elements)
__global__ __launch_bounds__(256) void redsum_kernel(const float* __restrict__ part,
                                                     const float* __restrict__ bias,
                                                     float* __restrict__ out, int Nd, int total) {
  int i = blockIdx.x * 256 + threadIdx.x;
  if (i < total) {
    int n = i % Nd;
    float s = bias[n];
#pragma unroll
    for (int c = 0; c < 16; ++c) s += part[(size_t)c * total + i];
    out[i] = s;
  }
}

// ---------------------------------------------------------------- final attention: S=3, dh=1024, 8 heads
__global__ __launch_bounds__(256) void attn3_kernel(const float* __restrict__ qkv, float* __restrict__ o) {
  const int b = blockIdx.x >> 3, h = blockIdx.x & 7;
  const float* base = qkv + (size_t)b * 3 * N3E;
  const int qo = h * 1024, ko = EDIM + h * 1024, vo = 2 * EDIM + h * 1024;
  float p[9] = {};
  for (int d = threadIdx.x; d < 1024; d += 256) {
    float q0 = base[qo + d], q1 = base[N3E + qo + d], q2 = base[2 * N3E + qo + d];
    float k0 = base[ko + d], k1 = base[N3E + ko + d], k2 = base[2 * N3E + ko + d];
    p[0] += q0 * k0; p[1] += q0 * k1; p[2] += q0 * k2;
    p[3] += q1 * k0; p[4] += q1 * k1; p[5] += q1 * k2;
    p[6] += q2 * k0; p[7] += q2 * k1; p[8] += q2 * k2;
  }
  __shared__ float red[4][9];
  __shared__ float aw[9];
  const int lane = threadIdx.x & 63, w = threadIdx.x >> 6;
#pragma unroll
  for (int e = 0; e < 9; ++e)
#pragma unroll
    for (int off = 32; off >= 1; off >>= 1) p[e] += __shfl_xor(p[e], off, 64);
  if (lane == 0)
#pragma unroll
    for (int e = 0; e < 9; ++e) red[w][e] = p[e];
  __syncthreads();
  if (threadIdx.x == 0) {
    float s[9];
#pragma unroll
    for (int e = 0; e < 9; ++e) s[e] = (red[0][e] + red[1][e] + red[2][e] + red[3][e]) / 32.f; // /sqrt(1024)
#pragma unroll
    for (int i = 0; i < 3; ++i) {
      float m = fmaxf(fmaxf(s[i * 3], s[i * 3 + 1]), s[i * 3 + 2]);
      float e0 = expf(s[i * 3] - m), e1 = expf(s[i * 3 + 1] - m), e2 = expf(s[i * 3 + 2] - m);
      float sm = e0 + e1 + e2;
      aw[i * 3] = e0 / sm; aw[i * 3 + 1] = e1 / sm; aw[i * 3 + 2] = e2 / sm;
    }
  }
  __syncthreads();
  for (int d = threadIdx.x; d < 1024; d += 256) {
    float v0 = base[vo + d], v1 = base[N3E + vo + d], v2 = base[2 * N3E + vo + d];
#pragma unroll
    for (int i = 0; i < 3; ++i)
      o[(size_t)(b * 3 + i) * EDIM + h * 1024 + d] = aw[i * 3] * v0 + aw[i * 3 + 1] * v1 + aw[i * 3 + 2] * v2;
  }
}

// ================================================================ launch
extern "C" void kernel_launch(void* const* d_in, const int* in_sizes, int n_in,
                              void* d_out, int out_size, void* d_ws, size_t ws_size,
                              hipStream_t stream) {
  const float* pc      = (const float*)d_in[0];
  const float* pe_w1   = (const float*)d_in[1];
  const float* pe_b1   = (const float*)d_in[2];
  const float* pe_w2   = (const float*)d_in[3];
  const float* pe_b2   = (const float*)d_in[4];
  const float* t_qkv_w = (const float*)d_in[5];
  const float* t_qkv_b = (const float*)d_in[6];
  const float* t_out_w = (const float*)d_in[7];
  const float* t_out_b = (const float*)d_in[8];
  const float* t_ln1_s = (const float*)d_in[9];
  const float* t_ln1_b = (const float*)d_in[10];
  const float* t_ff1_w = (const float*)d_in[11];
  const float* t_ff1_b = (const float*)d_in[12];
  const float* t_ff2_w = (const float*)d_in[13];
  const float* t_ff2_b = (const float*)d_in[14];
  const float* t_ln2_s = (const float*)d_in[15];
  const float* t_ln2_b = (const float*)d_in[16];
  const float* c1_w    = (const float*)d_in[17];
  const float* c1_b    = (const float*)d_in[18];
  const float* c2_w    = (const float*)d_in[19];
  const float* c2_b    = (const float*)d_in[20];
  const float* c3_w    = (const float*)d_in[21];
  const float* c3_b    = (const float*)d_in[22];
  const float* x_qkv_w = (const float*)d_in[23];
  const float* x_qkv_b = (const float*)d_in[24];
  const float* x_out_w = (const float*)d_in[25];
  const float* x_out_b = (const float*)d_in[26];
  float* outp = (float*)d_out;

  // workspace layout (peak dominated by transformer arena; partials alias it)
  char* wsp = (char*)d_ws;
  auto alloc = [&](size_t bytes) { char* q = wsp; wsp += (bytes + 255) & ~(size_t)255; return q; };
  float* centers = (float*)alloc((size_t)NBATCH * KCP * 3 * 4);
  float* pmax    = (float*)alloc(512 * 4);
  float* pmin    = (float*)alloc(512 * 4);
  float* Lv      = (float*)alloc(256);
  unsigned* tags = (unsigned*)alloc((size_t)NBATCH * RING * 64 * 4);                          // 16 KB
  unsigned long long* keyss = (unsigned long long*)alloc((size_t)NBATCH * RING * 64 * GPUB * 8); // 256 KB (adjacent to tags)
  float* mindbuf = (float*)alloc((size_t)NBATCH * NPTS * 4);                                  // 1 MB
  int* fstate    = (int*)alloc(256);
  float* x  = (float*)alloc((size_t)4096 * 256 * 4);
  float* xb = (float*)alloc((size_t)4096 * 256 * 4);
  float* arena = (float*)wsp;
  // transformer views
  float* qkvb = arena;
  float* ao   = qkvb + (size_t)4096 * 768;
  float* po   = ao + (size_t)4096 * 256;
  float* ffh  = po + (size_t)4096 * 256;
  float* ffo  = ffh + (size_t)4096 * 1024;
  // post-phase views (alias arena; transformer scratch dead by then)
  float* tri  = arena;
  float* z1   = tri + (size_t)NBATCH * 3 * 256 * 256;
  float* z2   = z1 + (size_t)12 * 512 * 64;
  float* z3   = z2 + (size_t)12 * 1024 * 16;
  float* qkv2 = z3 + (size_t)12 * 8192;
  float* at2  = qkv2 + (size_t)12 * N3E;
  float* mvp  = at2 + (size_t)12 * EDIM;   // 16 x 12 x N3E partials (18.9 MB, < transformer arena)
  (void)in_sizes; (void)n_in; (void)out_size; (void)ws_size; (void)ffo;

  // FPS mailbox must be zero every call (tags poll vs round#; 0 = not ready).
  hipMemsetAsync(tags, 0, (size_t)NBATCH * RING * 64 * 4 + (size_t)NBATCH * RING * 64 * GPUB * 8, stream);

  redmm_kernel<<<512, 256, 0, stream>>>(pc, NBATCH * NPTS * 3, pmax, pmin);
  redfin_kernel<<<1, 256, 0, stream>>>(pmax, pmin, 512, Lv);

  fps_kernel<<<NBATCH * FPS_NBLK, FPS_THR, 0, stream>>>(pc, centers, tags, keyss, mindbuf, fstate, 0);
  fps_kernel<<<NBATCH * FPS_NBLK, FPS_THR, 0, stream>>>(pc, centers, tags, keyss, mindbuf, fstate, 1);

  pe_kernel<<<NBATCH * KCP, 128, 0, stream>>>(centers, pe_w1, pe_b1, pe_w2, pe_b2, x);

  for (int l = 0; l < 2; ++l) {
    gemm_mfma_kernel<<<dim3(6, 32), 256, 0, stream>>>(x, t_qkv_w + (size_t)l * 256 * 768,
                                                      t_qkv_b + (size_t)l * 768, qkvb, 4096, 256, 768, 0);
    flash_mfma_kernel<<<dim3(16, 8, 4), 256, 0, stream>>>(qkvb, ao);
    gemm_mfma_kernel<<<dim3(2, 32), 256, 0, stream>>>(ao, t_out_w + (size_t)l * 256 * 256,
                                                      t_out_b + (size_t)l * 256, po, 4096, 256, 256, 0);
    ln_kernel<<<1024, 256, 0, stream>>>(x, po, t_ln1_s + (size_t)l * 256, t_ln1_b + (size_t)l * 256, xb);
    gemm_mfma_kernel<<<dim3(8, 32), 256, 0, stream>>>(xb, t_ff1_w + (size_t)l * 256 * 1024,
                                                      t_ff1_b + (size_t)l * 1024, ffh, 4096, 256, 1024, 1);
    gemm_mfma_kernel<<<dim3(2, 32), 256, 0, stream>>>(ffh, t_ff2_w + (size_t)l * 1024 * 256,
                                                      t_ff2_b + (size_t)l * 256, ffo, 4096, 1024, 256, 0);
    ln_kernel<<<1024, 256, 0, stream>>>(xb, ffo, t_ln2_s + (size_t)l * 256, t_ln2_b + (size_t)l * 256, x);
  }

  // scatter to tri-planes (zero first: atomic accumulation, and arena was reused)
  hipMemsetAsync(tri, 0, (size_t)NBATCH * 3 * 256 * 256 * 4, stream);
  scatter_kernel<<<NBATCH * KCP, 256, 0, stream>>>(x, centers, Lv, tri);

  conv_kernel<256, 512, 16, 16, 8, 8, 4, 32><<<dim3(12, 128), 256, 0, stream>>>(tri, c1_w, c1_b, z1);
  conv_kernel<512, 1024, 8, 8, 4, 4, 16, 128><<<dim3(12, 64), 256, 0, stream>>>(z1, c2_w, c2_b, z2);
  conv3g_kernel<<<2048, 256, 0, stream>>>(z2, c3_w, c3_b, z3);

  // qkv2 = z3 @ x_qkv_w + b : K-split float4 partials (no atomics) + fused reduce
  matvec_part4_kernel<12, 512><<<dim3(N3E / 1024, 16), 256, 0, stream>>>(z3, x_qkv_w, mvp, EDIM, N3E);
  redsum_kernel<<<(12 * N3E + 255) / 256, 256, 0, stream>>>(mvp, x_qkv_b, qkv2, N3E, 12 * N3E);

  attn3_kernel<<<32, 256, 0, stream>>>(qkv2, at2);

  matvec_part4_kernel<12, 512><<<dim3(EDIM / 1024, 16), 256, 0, stream>>>(at2, x_out_w, mvp, EDIM, EDIM);
  redsum_kernel<<<(12 * EDIM + 255) / 256, 256, 0, stream>>>(mvp, x_out_b, outp, EDIM, 12 * EDIM);
}

// Round 17
// 4350.534 us; speedup vs baseline: 1.5161x; 1.0015x over previous
//
#include <hip/hip_runtime.h>
#include <math.h>

// Problem constants
#define NPTS   65536
#define NBATCH 4
#define KCP    1024      // NCP centers
#define DM     256
#define FFD    1024
#define EDIM   8192      // E
#define N3E    24576     // 3*E

// FPS decomposition: 16 blocks/batch x 256 threads (4 waves); 64 publisher-waves
// per batch, each wave owns 1024 points (16/thread) held in registers.
#define FPS_NBLK 16
#define FPS_THR  256
#define FPS_PPT  16
#define GPUB     8       // keys published per wave per round (last one = bound) [empirical optimum]
#define HARV_MAX 16      // max winners harvested per global sync round
#define RING     16      // mailbox ring depth (rounds)

typedef __attribute__((ext_vector_type(8))) short short8v;
typedef __attribute__((ext_vector_type(4))) short short4v;
typedef __attribute__((ext_vector_type(4))) float float4v;

__device__ __forceinline__ unsigned long long umaxll(unsigned long long a, unsigned long long b) {
  return a > b ? a : b;
}

__device__ __forceinline__ short bf16rn(float f) {
  unsigned u = __float_as_uint(f);
  return (short)((u + 0x7FFFu + ((u >> 16) & 1u)) >> 16);
}

// ---------------------------------------------------------------- global min/max (for L)
__global__ __launch_bounds__(256) void redmm_kernel(const float* __restrict__ v, int n,
                                                    float* __restrict__ pmax, float* __restrict__ pmin) {
  float mx = -INFINITY, mn = INFINITY;
  for (int i = blockIdx.x * 256 + threadIdx.x; i < n; i += gridDim.x * 256) {
    float x = v[i]; mx = fmaxf(mx, x); mn = fminf(mn, x);
  }
#pragma unroll
  for (int off = 32; off >= 1; off >>= 1) {
    mx = fmaxf(mx, __shfl_xor(mx, off, 64));
    mn = fminf(mn, __shfl_xor(mn, off, 64));
  }
  __shared__ float smx[4], smn[4];
  int lane = threadIdx.x & 63, w = threadIdx.x >> 6;
  if (lane == 0) { smx[w] = mx; smn[w] = mn; }
  __syncthreads();
  if (threadIdx.x == 0) {
    pmax[blockIdx.x] = fmaxf(fmaxf(smx[0], smx[1]), fmaxf(smx[2], smx[3]));
    pmin[blockIdx.x] = fminf(fminf(smn[0], smn[1]), fminf(smn[2], smn[3]));
  }
}

__global__ __launch_bounds__(256) void redfin_kernel(const float* __restrict__ pmax,
                                                     const float* __restrict__ pmin, int nb,
                                                     float* __restrict__ Lv) {
  float mx = -INFINITY, mn = INFINITY;
  for (int i = threadIdx.x; i < nb; i += 256) { mx = fmaxf(mx, pmax[i]); mn = fminf(mn, pmin[i]); }
#pragma unroll
  for (int off = 32; off >= 1; off >>= 1) {
    mx = fmaxf(mx, __shfl_xor(mx, off, 64));
    mn = fminf(mn, __shfl_xor(mn, off, 64));
  }
  __shared__ float smx[4], smn[4];
  int lane = threadIdx.x & 63, w = threadIdx.x >> 6;
  if (lane == 0) { smx[w] = mx; smn[w] = mn; }
  __syncthreads();
  if (threadIdx.x == 0) {
    mx = fmaxf(fmaxf(smx[0], smx[1]), fmaxf(smx[2], smx[3]));
    mn = fminf(fminf(smn[0], smn[1]), fminf(smn[2], smn[3]));
    Lv[0] = __fsub_rn(mx, mn);
  }
}

// ---------------------------------------------------------------- FPS: top-8 harvesting, single-poller, one dispatch
__global__ __launch_bounds__(FPS_THR, 1) void fps_kernel(const float* __restrict__ pc,
                                                         float* __restrict__ centers,
                                                         unsigned* __restrict__ tags,
                                                         unsigned long long* __restrict__ keys) {
  const int blk = blockIdx.x;
  const int b = blk / FPS_NBLK, bb = blk % FPS_NBLK;
  const int tid = threadIdx.x;
  const int lane = tid & 63, wv = tid >> 6;
  const int wvg = bb * 4 + wv;                 // wave id in batch: 0..63
  const float* pcb = pc + (size_t)b * NPTS * 3;

  __shared__ float kpts[96];
  __shared__ float wlds[2][HARV_MAX][3];
  __shared__ int hcnt[2];

  float px[FPS_PPT], py[FPS_PPT], pz[FPS_PPT], mind[FPS_PPT];
  const int gbase = wvg * 1024;                // 1024 points per wave
#pragma unroll
  for (int i = 0; i < FPS_PPT; ++i) {
    int g = gbase + i * 64 + lane;
    px[i] = pcb[3 * g]; py[i] = pcb[3 * g + 1]; pz[i] = pcb[3 * g + 2];
  }
  for (int i = tid; i < 96; i += FPS_THR) kpts[i] = pcb[i];
  __syncthreads();   // kpts ready

  unsigned* const tagb = tags + (size_t)b * RING * 64;                   // [RING][64] u32
  unsigned long long* const keyb = keys + (size_t)b * RING * 64 * GPUB;  // [RING][64][GPUB]

  // --- round 1: density over first 32 points (IEEE f32, op-for-op) -> center 0
  {
    unsigned long long bk = 0ull;
#pragma unroll
    for (int i = 0; i < FPS_PPT; ++i) {
      float acc = 0.f;
      for (int j = 0; j < 32; ++j) {
        float dx = __fsub_rn(px[i], kpts[3 * j]);
        float dy = __fsub_rn(py[i], kpts[3 * j + 1]);
        float dz = __fsub_rn(pz[i], kpts[3 * j + 2]);
        float ss = __fadd_rn(__fadd_rn(__fmul_rn(dx, dx), __fmul_rn(dy, dy)), __fmul_rn(dz, dz));
        float d = __fsqrt_rn(ss);
        float dd = __fadd_rn(__fmul_rn(d, d), 1e-6f);
        acc = __fadd_rn(acc, expf(__fdiv_rn(-0.02f, dd)));
      }
      float dens = __fdiv_rn(acc, 32.f);
      int g = gbase + i * 64 + lane;
      bk = umaxll(bk, ((unsigned long long)__float_as_uint(dens) << 32) | (unsigned int)(~g));
    }
#pragma unroll
    for (int off = 1; off < 64; off <<= 1) bk = umaxll(bk, __shfl_xor(bk, off, 64));
    if (lane == 0) {
      keyb[(size_t)(1 & (RING - 1)) * 64 * GPUB + wvg * GPUB] = bk;
      __hip_atomic_store(&tagb[(1 & (RING - 1)) * 64 + wvg], 1u, __ATOMIC_RELEASE, __HIP_MEMORY_SCOPE_AGENT);
    }
    unsigned tag;
    do {
      tag = __hip_atomic_load(&tagb[(1 & (RING - 1)) * 64 + lane], __ATOMIC_ACQUIRE, __HIP_MEMORY_SCOPE_AGENT);
    } while (__any(tag != 1u));
    unsigned long long k2 = __hip_atomic_load(&keyb[(size_t)(1 & (RING - 1)) * 64 * GPUB + lane * GPUB],
                                              __ATOMIC_RELAXED, __HIP_MEMORY_SCOPE_AGENT);
#pragma unroll
    for (int off = 1; off < 64; off <<= 1) k2 = umaxll(k2, __shfl_xor(k2, off, 64));
    int widx = (int)(~(unsigned)(k2 & 0xFFFFFFFFull));
    float wx = pcb[3 * widx], wy = pcb[3 * widx + 1], wz = pcb[3 * widx + 2];
    if (wvg == 0 && lane == 0) {
      centers[(size_t)b * KCP * 3 + 0] = wx;
      centers[(size_t)b * KCP * 3 + 1] = wy;
      centers[(size_t)b * KCP * 3 + 2] = wz;
    }
#pragma unroll
    for (int i = 0; i < FPS_PPT; ++i) {
      float dx = __fsub_rn(px[i], wx), dy = __fsub_rn(py[i], wy), dz = __fsub_rn(pz[i], wz);
      mind[i] = __fsqrt_rn(__fadd_rn(__fadd_rn(__fmul_rn(dx, dx), __fmul_rn(dy, dy)), __fmul_rn(dz, dz)));
    }
  }

  int t = 1;
  for (int r = 2; t < KCP; ++r) {
    // every wave: fresh keys + extract top-8 (keys only)
    unsigned long long tk[FPS_PPT];
#pragma unroll
    for (int i = 0; i < FPS_PPT; ++i) {
      int g = gbase + i * 64 + lane;
      tk[i] = ((unsigned long long)__float_as_uint(mind[i]) << 32) | (unsigned int)(~g);
    }
    unsigned long long ek[GPUB];
#pragma unroll
    for (int g = 0; g < GPUB; ++g) {
      unsigned long long lbk = 0ull;
#pragma unroll
      for (int i = 0; i < FPS_PPT; ++i) lbk = umaxll(lbk, tk[i]);
      unsigned long long wk = lbk;
#pragma unroll
      for (int off = 1; off < 64; off <<= 1) wk = umaxll(wk, __shfl_xor(wk, off, 64));
      ek[g] = wk;
#pragma unroll
      for (int i = 0; i < FPS_PPT; ++i)
        if (tk[i] == wk) tk[i] = 0ull;
    }
    const int ri = r & (RING - 1);
    if (lane == 0) {
      unsigned long long* sp = keyb + ((size_t)ri * 64 + wvg) * GPUB;
#pragma unroll
      for (int g = 0; g < GPUB; ++g)
        __hip_atomic_store(&sp[g], ek[g], __ATOMIC_RELAXED, __HIP_MEMORY_SCOPE_AGENT);
      __hip_atomic_store(&tagb[ri * 64 + wvg], (unsigned)r, __ATOMIC_RELEASE, __HIP_MEMORY_SCOPE_AGENT);
    }

    if (wv == 0) {
      // single poller: wave 0 of each block
      unsigned tag;
      do {
        tag = __hip_atomic_load(&tagb[ri * 64 + lane], __ATOMIC_ACQUIRE, __HIP_MEMORY_SCOPE_AGENT);
      } while (__any(tag != (unsigned)r));
      const unsigned long long* pl = keyb + ((size_t)ri * 64 + lane) * GPUB;
      unsigned long long ck[GPUB];
#pragma unroll
      for (int e = 0; e < GPUB; ++e)
        ck[e] = __hip_atomic_load(&pl[e], __ATOMIC_RELAXED, __HIP_MEMORY_SCOPE_AGENT);
      float cx[GPUB], cy[GPUB], cz[GPUB];
#pragma unroll
      for (int e = 0; e < GPUB; ++e) {
        int gi = (int)(~(unsigned)(ck[e] & 0xFFFFFFFFull));
        cx[e] = pcb[3 * gi]; cy[e] = pcb[3 * gi + 1]; cz[e] = pcb[3 * gi + 2];
      }
      unsigned long long u = ck[GPUB - 1];
#pragma unroll
      for (int off = 1; off < 64; off <<= 1) u = umaxll(u, __shfl_xor(u, off, 64));
      int h = 0, tl = t;
      while (true) {
        unsigned long long lb = 0ull; float lx = 0.f, ly = 0.f, lz = 0.f;
#pragma unroll
        for (int e = 0; e < GPUB; ++e)
          if (ck[e] > lb) { lb = ck[e]; lx = cx[e]; ly = cy[e]; lz = cz[e]; }
        unsigned long long wk = lb;
#pragma unroll
        for (int off = 1; off < 64; off <<= 1) wk = umaxll(wk, __shfl_xor(wk, off, 64));
        if (h > 0 && wk < u) break;   // h==0 pick is always the true global argmax
        int owner = __ffsll(__ballot(lb == wk)) - 1;
        float wx = __shfl(lx, owner, 64), wy = __shfl(ly, owner, 64), wz = __shfl(lz, owner, 64);
        if (lane == 0) {
          wlds[r & 1][h][0] = wx; wlds[r & 1][h][1] = wy; wlds[r & 1][h][2] = wz;
          if (bb == 0) {
            centers[((size_t)b * KCP + tl) * 3 + 0] = wx;
            centers[((size_t)b * KCP + tl) * 3 + 1] = wy;
            centers[((size_t)b * KCP + tl) * 3 + 2] = wz;
          }
        }
#pragma unroll
        for (int e = 0; e < GPUB; ++e) {
          float dx = __fsub_rn(cx[e], wx), dy = __fsub_rn(cy[e], wy), dz = __fsub_rn(cz[e], wz);
          float d = __fsqrt_rn(__fadd_rn(__fadd_rn(__fmul_rn(dx, dx), __fmul_rn(dy, dy)), __fmul_rn(dz, dz)));
          float ov = __uint_as_float((unsigned)(ck[e] >> 32));
          float nv = fminf(ov, d);
          ck[e] = ((unsigned long long)__float_as_uint(nv) << 32) | (ck[e] & 0xFFFFFFFFull);
        }
        ++h; ++tl;
        if (h == HARV_MAX || tl == KCP) break;
      }
      if (lane == 0) hcnt[r & 1] = h;
    }
    __syncthreads();
    const int h = hcnt[r & 1];
    for (int j = 0; j < h; ++j) {
      float wx = wlds[r & 1][j][0], wy = wlds[r & 1][j][1], wz = wlds[r & 1][j][2];
#pragma unroll
      for (int i = 0; i < FPS_PPT; ++i) {
        float dx = __fsub_rn(px[i], wx), dy = __fsub_rn(py[i], wy), dz = __fsub_rn(pz[i], wz);
        float d = __fsqrt_rn(__fadd_rn(__fadd_rn(__fmul_rn(dx, dx), __fmul_rn(dy, dy)), __fmul_rn(dz, dz)));
        mind[i] = fminf(mind[i], d);
      }
    }
    t += h;
  }
}

// ---------------------------------------------------------------- point encoder + pos-emb -> x (B,K,256)
__global__ __launch_bounds__(128) void pe_kernel(const float* __restrict__ centers,
                                                 const float* __restrict__ w1, const float* __restrict__ b1,
                                                 const float* __restrict__ w2, const float* __restrict__ b2,
                                                 float* __restrict__ x) {
  const int p = blockIdx.x;      // b*K + k
  const int d = threadIdx.x;     // 0..127
  __shared__ float h[128];
  __shared__ float c[3];
  if (d < 3) c[d] = centers[(size_t)p * 3 + d];
  __syncthreads();
  float hv = b1[d];
#pragma unroll
  for (int j = 0; j < 3; ++j) hv += c[j] * w1[j * 128 + d];
  hv = fmaxf(hv, 0.f);
  h[d] = hv;
  __syncthreads();
  float f = b2[d];
  for (int j = 0; j < 128; ++j) f += h[j] * w2[j * 128 + d];
  x[(size_t)p * 256 + d] = f;
  if (d < 64) {
    float fr = expf(__fmul_rn((float)d, -0.14619587892025696f)); // -ln(10000)/63
    float ssum = 0.f, csum = 0.f;
#pragma unroll
    for (int a = 0; a < 3; ++a) {
      float e = __fmul_rn(c[a], fr);
      ssum += sinf(e); csum += cosf(e);
    }
    x[(size_t)p * 256 + 128 + d] = __fdiv_rn(ssum, 3.f);
    x[(size_t)p * 256 + 192 + d] = __fdiv_rn(csum, 3.f);
  }
}

// ---------------------------------------------------------------- bf16 MFMA GEMM: C = A(M,K)@W(K,N)+bias [relu]
// 128x128 tile, 4 waves x (64x64)
__global__ __launch_bounds__(256) void gemm_mfma_kernel(const float* __restrict__ A,
                                                        const float* __restrict__ W,
                                                        const float* __restrict__ bias,
                                                        float* __restrict__ C,
                                                        int M, int Kd, int Nd, int relu) {
  __shared__ __align__(16) short Al[128][40];
  __shared__ __align__(16) short Wl[128][40];
  const int bm = blockIdx.y * 128, bn = blockIdx.x * 128;
  const int tid = threadIdx.x;
  const int lane = tid & 63, wv = tid >> 6;
  const int wr = wv >> 1, wc = wv & 1;
  const int l15 = lane & 15, lk = lane >> 4;

  float4v acc[4][4];
#pragma unroll
  for (int i = 0; i < 4; ++i)
#pragma unroll
    for (int j = 0; j < 4; ++j) acc[i][j] = (float4v){0.f, 0.f, 0.f, 0.f};

  for (int k0 = 0; k0 < Kd; k0 += 32) {
    __syncthreads();
#pragma unroll
    for (int i = 0; i < 4; ++i) {
      int idx = (i * 256 + tid) * 4;        // 0..4095
      int m = idx >> 5, k = idx & 31;
      float4 v = *(const float4*)&A[(size_t)(bm + m) * Kd + k0 + k];
      short4v s = { bf16rn(v.x), bf16rn(v.y), bf16rn(v.z), bf16rn(v.w) };
      *(short4v*)&Al[m][k] = s;
    }
#pragma unroll
    for (int i = 0; i < 4; ++i) {
      int task = i * 256 + tid;
      int n = task & 127, c = task >> 7;
      short4v s;
#pragma unroll
      for (int j = 0; j < 4; ++j)
        s[j] = bf16rn(W[(size_t)(k0 + c * 4 + j) * Nd + bn + n]);
      *(short4v*)&Wl[n][c * 4] = s;
    }
    __syncthreads();
    short8v af[4], bf[4];
#pragma unroll
    for (int mf = 0; mf < 4; ++mf)
      af[mf] = *(const short8v*)&Al[wr * 64 + mf * 16 + l15][lk * 8];
#pragma unroll
    for (int nf = 0; nf < 4; ++nf)
      bf[nf] = *(const short8v*)&Wl[wc * 64 + nf * 16 + l15][lk * 8];
#pragma unroll
    for (int mf = 0; mf < 4; ++mf)
#pragma unroll
      for (int nf = 0; nf < 4; ++nf)
        acc[mf][nf] = __builtin_amdgcn_mfma_f32_16x16x32_bf16(af[mf], bf[nf], acc[mf][nf], 0, 0, 0);
  }

#pragma unroll
  for (int mf = 0; mf < 4; ++mf) {
    int row = bm + wr * 64 + mf * 16 + lk * 4;
#pragma unroll
    for (int nf = 0; nf < 4; ++nf) {
      int col = bn + wc * 64 + nf * 16 + l15;
      float bv = bias[col];
#pragma unroll
      for (int j = 0; j < 4; ++j) {
        float v = acc[mf][nf][j] + bv;
        if (relu) v = fmaxf(v, 0.f);
        C[(size_t)(row + j) * Nd + col] = v;
      }
    }
  }
}

// ---------------------------------------------------------------- bf16 MFMA GEMM, 64-row tile (for N=256 GEMMs):
// 64x128 tile, 2 waves x (64x64). 2x block count vs 128-row tile -> occupancy.
// Same K order + MFMA sequence per output as gemm_mfma_kernel -> bit-identical.
__global__ __launch_bounds__(128) void gemm64_mfma_kernel(const float* __restrict__ A,
                                                          const float* __restrict__ W,
                                                          const float* __restrict__ bias,
                                                          float* __restrict__ C,
                                                          int M, int Kd, int Nd, int relu) {
  __shared__ __align__(16) short Al[64][40];
  __shared__ __align__(16) short Wl[128][40];
  const int bm = blockIdx.y * 64, bn = blockIdx.x * 128;
  const int tid = threadIdx.x;          // 0..127
  const int lane = tid & 63, wv = tid >> 6;   // 2 waves; wv = column half
  const int l15 = lane & 15, lk = lane >> 4;

  float4v acc[4][4];
#pragma unroll
  for (int i = 0; i < 4; ++i)
#pragma unroll
    for (int j = 0; j < 4; ++j) acc[i][j] = (float4v){0.f, 0.f, 0.f, 0.f};

  for (int k0 = 0; k0 < Kd; k0 += 32) {
    __syncthreads();
#pragma unroll
    for (int i = 0; i < 4; ++i) {
      int idx = (i * 128 + tid) * 4;        // 0..2047
      int m = idx >> 5, k = idx & 31;
      float4 v = *(const float4*)&A[(size_t)(bm + m) * Kd + k0 + k];
      short4v s = { bf16rn(v.x), bf16rn(v.y), bf16rn(v.z), bf16rn(v.w) };
      *(short4v*)&Al[m][k] = s;
    }
#pragma unroll
    for (int i = 0; i < 8; ++i) {
      int task = i * 128 + tid;
      int n = task & 127, c = task >> 7;
      short4v s;
#pragma unroll
      for (int j = 0; j < 4; ++j)
        s[j] = bf16rn(W[(size_t)(k0 + c * 4 + j) * Nd + bn + n]);
      *(short4v*)&Wl[n][c * 4] = s;
    }
    __syncthreads();
    short8v af[4], bf[4];
#pragma unroll
    for (int mf = 0; mf < 4; ++mf)
      af[mf] = *(const short8v*)&Al[mf * 16 + l15][lk * 8];
#pragma unroll
    for (int nf = 0; nf < 4; ++nf)
      bf[nf] = *(const short8v*)&Wl[wv * 64 + nf * 16 + l15][lk * 8];
#pragma unroll
    for (int mf = 0; mf < 4; ++mf)
#pragma unroll
      for (int nf = 0; nf < 4; ++nf)
        acc[mf][nf] = __builtin_amdgcn_mfma_f32_16x16x32_bf16(af[mf], bf[nf], acc[mf][nf], 0, 0, 0);
  }

#pragma unroll
  for (int mf = 0; mf < 4; ++mf) {
    int row = bm + mf * 16 + lk * 4;
#pragma unroll
    for (int nf = 0; nf < 4; ++nf) {
      int col = bn + wv * 64 + nf * 16 + l15;
      float bv = bias[col];
#pragma unroll
      for (int j = 0; j < 4; ++j) {
        float v = acc[mf][nf][j] + bv;
        if (relu) v = fmaxf(v, 0.f);
        C[(size_t)(row + j) * Nd + col] = v;
      }
    }
  }
}

// ---------------------------------------------------------------- MFMA flash attention (S=1024, dh=32, nh=8)
__global__ __launch_bounds__(256, 1) void flash_mfma_kernel(const float* __restrict__ qkv,
                                                            float* __restrict__ ao) {
  const int qt = blockIdx.x, h = blockIdx.y, b = blockIdx.z;
  const int tid = threadIdx.x;
  const int lane = tid & 63, w = tid >> 6;
  const int l15 = lane & 15, lk = lane >> 4;
  const int q0 = qt * 64;

  __shared__ __align__(16) short Kc[64][40];    // [key][dim]
  __shared__ __align__(16) short Vt[32][72];    // [dim][key] (transposed)
  __shared__ __align__(16) short Plds[4][16][72]; // per-wave [q][key]

  short8v qa;
  {
    const float* qr = qkv + (size_t)(b * 1024 + q0 + w * 16 + l15) * 768 + h * 32 + lk * 8;
    float4 a = *(const float4*)qr;
    float4 c = *(const float4*)(qr + 4);
    qa = (short8v){ bf16rn(a.x), bf16rn(a.y), bf16rn(a.z), bf16rn(a.w),
                    bf16rn(c.x), bf16rn(c.y), bf16rn(c.z), bf16rn(c.w) };
  }

  float4v o0 = (float4v){0.f, 0.f, 0.f, 0.f};
  float4v o1 = (float4v){0.f, 0.f, 0.f, 0.f};
  float m_cur[4] = { -INFINITY, -INFINITY, -INFINITY, -INFINITY };
  float l_part[4] = { 0.f, 0.f, 0.f, 0.f };
  const float scale = 0.17677669529663687f;   // 1/sqrt(32)

  for (int c0 = 0; c0 < 1024; c0 += 64) {
    __syncthreads();
    {
      int key = tid >> 2, dblk = (tid & 3) * 8;
      size_t row = (size_t)(b * 1024 + c0 + key) * 768 + h * 32 + dblk;
      float4 k1 = *(const float4*)&qkv[row + 256];
      float4 k2 = *(const float4*)&qkv[row + 260];
      short8v ks = (short8v){ bf16rn(k1.x), bf16rn(k1.y), bf16rn(k1.z), bf16rn(k1.w),
                              bf16rn(k2.x), bf16rn(k2.y), bf16rn(k2.z), bf16rn(k2.w) };
      *(short8v*)&Kc[key][dblk] = ks;
      float4 v1 = *(const float4*)&qkv[row + 512];
      float4 v2 = *(const float4*)&qkv[row + 516];
      Vt[dblk + 0][key] = bf16rn(v1.x); Vt[dblk + 1][key] = bf16rn(v1.y);
      Vt[dblk + 2][key] = bf16rn(v1.z); Vt[dblk + 3][key] = bf16rn(v1.w);
      Vt[dblk + 4][key] = bf16rn(v2.x); Vt[dblk + 5][key] = bf16rn(v2.y);
      Vt[dblk + 6][key] = bf16rn(v2.z); Vt[dblk + 7][key] = bf16rn(v2.w);
    }
    __syncthreads();

    float4v s[4];
#pragma unroll
    for (int f = 0; f < 4; ++f) {
      short8v kb = *(const short8v*)&Kc[f * 16 + l15][lk * 8];
      float4v z = (float4v){0.f, 0.f, 0.f, 0.f};
      s[f] = __builtin_amdgcn_mfma_f32_16x16x32_bf16(qa, kb, z, 0, 0, 0);
    }
#pragma unroll
    for (int f = 0; f < 4; ++f)
#pragma unroll
      for (int j = 0; j < 4; ++j) s[f][j] *= scale;

    float corr[4];
#pragma unroll
    for (int j = 0; j < 4; ++j) {
      float v = fmaxf(fmaxf(s[0][j], s[1][j]), fmaxf(s[2][j], s[3][j]));
#pragma unroll
      for (int off = 1; off < 16; off <<= 1) v = fmaxf(v, __shfl_xor(v, off, 64));
      float m_new = fmaxf(m_cur[j], v);
      corr[j] = expf(m_cur[j] - m_new);
      m_cur[j] = m_new;
    }
#pragma unroll
    for (int f = 0; f < 4; ++f)
#pragma unroll
      for (int j = 0; j < 4; ++j) {
        float p = expf(s[f][j] - m_cur[j]);
        s[f][j] = p;
        Plds[w][lk * 4 + j][f * 16 + l15] = bf16rn(p);
      }
#pragma unroll
    for (int j = 0; j < 4; ++j) {
      float tsum = s[0][j] + s[1][j] + s[2][j] + s[3][j];
#pragma unroll
      for (int off = 1; off < 16; off <<= 1) tsum += __shfl_xor(tsum, off, 64);
      l_part[j] = l_part[j] * corr[j] + tsum;
      o0[j] *= corr[j];
      o1[j] *= corr[j];
    }
    asm volatile("s_waitcnt lgkmcnt(0)" ::: "memory");
    __builtin_amdgcn_sched_barrier(0);

#pragma unroll
    for (int kb = 0; kb < 2; ++kb) {
      short8v pa = *(const short8v*)&Plds[w][l15][kb * 32 + lk * 8];
      short8v vb0 = *(const short8v*)&Vt[l15][kb * 32 + lk * 8];
      short8v vb1 = *(const short8v*)&Vt[16 + l15][kb * 32 + lk * 8];
      o0 = __builtin_amdgcn_mfma_f32_16x16x32_bf16(pa, vb0, o0, 0, 0, 0);
      o1 = __builtin_amdgcn_mfma_f32_16x16x32_bf16(pa, vb1, o1, 0, 0, 0);
    }
  }

#pragma unroll
  for (int j = 0; j < 4; ++j) {
    float inv = 1.f / l_part[j];
    int q = q0 + w * 16 + lk * 4 + j;
    float* orow = ao + (size_t)(b * 1024 + q) * 256 + h * 32;
    orow[l15] = o0[j] * inv;
    orow[16 + l15] = o1[j] * inv;
  }
}

// ---------------------------------------------------------------- fused residual + LayerNorm (rows of 256)
__global__ __launch_bounds__(256) void ln_kernel(const float* __restrict__ a, const float* __restrict__ r,
                                                 const float* __restrict__ sc, const float* __restrict__ bi,
                                                 float* __restrict__ out) {
  const int row = blockIdx.x * 4 + (threadIdx.x >> 6);
  const int lane = threadIdx.x & 63;
  const float* ar = a + (size_t)row * 256;
  const float* rr = r + (size_t)row * 256;
  float v[4];
#pragma unroll
  for (int i = 0; i < 4; ++i) v[i] = ar[lane + 64 * i] + rr[lane + 64 * i];
  float s = v[0] + v[1] + v[2] + v[3];
#pragma unroll
  for (int off = 32; off >= 1; off >>= 1) s += __shfl_xor(s, off, 64);
  float mean = s * (1.f / 256.f);
  float vs = 0.f;
#pragma unroll
  for (int i = 0; i < 4; ++i) { float d = v[i] - mean; vs += d * d; }
#pragma unroll
  for (int off = 32; off >= 1; off >>= 1) vs += __shfl_xor(vs, off, 64);
  float var = vs * (1.f / 256.f);
  float rstd = 1.f / sqrtf(var + 1e-5f);
  float* orow = out + (size_t)row * 256;
#pragma unroll
  for (int i = 0; i < 4; ++i) {
    int d = lane + 64 * i;
    orow[d] = (v[i] - mean) * rstd * sc[d] + bi[d];
  }
}

// ---------------------------------------------------------------- scatter x onto tri-planes (B,3,C,16,16)
__global__ __launch_bounds__(256) void scatter_kernel(const float* __restrict__ x,
                                                      const float* __restrict__ centers,
                                                      const float* __restrict__ Lv,
                                                      float* __restrict__ tri) {
  const int pnt = blockIdx.x;  // b*K + k
  const int b = pnt >> 10;
  const int tid = threadIdx.x;
  __shared__ int g[3];
  if (tid == 0) {
    float L = Lv[0];
    float half = __fmul_rn(L, 0.5f);
#pragma unroll
    for (int a = 0; a < 3; ++a) {
      float c = centers[(size_t)pnt * 3 + a];
      float t = __fmul_rn(__fdiv_rn(__fadd_rn(c, half), L), 16.f);
      int gi = (int)t;               // trunc toward zero, matches astype(int32)
      g[a] = min(15, max(0, gi));
    }
  }
  __syncthreads();
  const int gx = g[0], gy = g[1], gz = g[2];
  float v = x[(size_t)pnt * 256 + tid];
  float* trib = tri + (size_t)b * 3 * 256 * 256;
  atomicAdd(&trib[(0 * 256 + tid) * 256 + gy * 16 + gx], v);
  atomicAdd(&trib[(1 * 256 + tid) * 256 + gz * 16 + gy], v);
  atomicAdd(&trib[(2 * 256 + tid) * 256 + gz * 16 + gx], v);
}

// ---------------------------------------------------------------- direct conv 3x3 stride2 pad1 + bias + relu
template <int IC, int OC, int IH, int IW, int OH, int OW, int OCT, int ICC>
__global__ __launch_bounds__(256, 1) void conv_kernel(const float* __restrict__ in, const float* __restrict__ w,
                                                      const float* __restrict__ bias, float* __restrict__ out) {
  __shared__ float lin[ICC * IH * IW];
  const int n = blockIdx.x;
  const int oc = blockIdx.y * OCT + threadIdx.x / (OH * OW);
  const int sp = threadIdx.x % (OH * OW);
  const int oy = sp / OW, ox = sp % OW;
  const int iy0 = oy * 2 - 1, ix0 = ox * 2 - 1;
  float acc = 0.f;
  for (int c0 = 0; c0 < IC; c0 += ICC) {
    __syncthreads();
    for (int i = threadIdx.x; i < ICC * IH * IW; i += 256)
      lin[i] = in[((size_t)n * IC + c0) * (IH * IW) + i];
    __syncthreads();
    const float* wp = w + ((size_t)oc * IC + c0) * 9;
    for (int ic = 0; ic < ICC; ++ic) {
      const float* wr = wp + (size_t)ic * 9;
      const float* lr = lin + ic * IH * IW;
#pragma unroll
      for (int ky = 0; ky < 3; ++ky) {
        int iy = iy0 + ky;
        if (iy >= 0 && iy < IH) {
#pragma unroll
          for (int kx = 0; kx < 3; ++kx) {
            int ix = ix0 + kx;
            if (ix >= 0 && ix < IW) acc += lr[iy * IW + ix] * wr[ky * 3 + kx];
          }
        }
      }
    }
  }
  out[((size_t)n * OC + oc) * (OH * OW) + sp] = fmaxf(acc + bias[oc], 0.f);
}

// ---------------------------------------------------------------- conv3 weights-once + full occupancy (2048 blocks)
__global__ __launch_bounds__(256, 1) void conv3g_kernel(const float* __restrict__ in,
                                                        const float* __restrict__ w,
                                                        const float* __restrict__ bias,
                                                        float* __restrict__ out) {
  __shared__ float wl[9216];
  __shared__ float psum[48][4];
  const int oc = blockIdx.x;
  const int tid = threadIdx.x;
  const float4* w4 = (const float4*)(w + (size_t)oc * 9216);
  for (int i = tid; i < 2304; i += 256)
    ((float4*)wl)[i] = w4[i];
  __syncthreads();
  if (tid < 192) {
    const int o = tid % 48, c = tid / 48;
    const int n = o >> 2, sp = o & 3;
    const int oy = sp >> 1, ox = sp & 1;
    const int iy0 = oy * 2 - 1, ix0 = ox * 2 - 1;
    float acc = 0.f;
    const float* inb = in + ((size_t)n * 1024 + c * 256) * 16;
    const float* wb = wl + c * 256 * 9;
    for (int ic = 0; ic < 256; ++ic) {
      const float* lr = inb + ic * 16;
      const float* wr = wb + ic * 9;
#pragma unroll
      for (int ky = 0; ky < 3; ++ky) {
        int iy = iy0 + ky;
        if (iy >= 0 && iy < 4) {
#pragma unroll
          for (int kx = 0; kx < 3; ++kx) {
            int ix = ix0 + kx;
            if (ix >= 0 && ix < 4) acc += lr[iy * 4 + ix] * wr[ky * 3 + kx];
          }
        }
      }
    }
    psum[o][c] = acc;
  }
  __syncthreads();
  if (tid < 48) {
    float s = ((psum[tid][0] + psum[tid][1]) + psum[tid][2]) + psum[tid][3];
    int n = tid >> 2, sp = tid & 3;
    out[((size_t)n * 2048 + oc) * 4 + sp] = fmaxf(s + bias[oc], 0.f);
  }
}

// ---------------------------------------------------------------- K-split matvec partials, float4 columns per thread
template <int M, int KC>
__global__ __launch_bounds__(256, 1) void matvec_part4_kernel(const float* __restrict__ A,
                                                              const float* __restrict__ W,
                                                              float* __restrict__ part,
                                                              int Kd, int Nd) {
  __shared__ float Al[KC * M];
  const int tid = threadIdx.x;
  const int n4 = blockIdx.x * 256 + tid;    // float4 column index
  const int nd4 = Nd >> 2;
  const int k0 = blockIdx.y * KC;
  for (int i = tid; i < KC * M; i += 256) {
    int k = i / M, m = i - k * M;
    Al[i] = A[(size_t)m * Kd + k0 + k];
  }
  __syncthreads();
  float4 acc[M];
#pragma unroll
  for (int m = 0; m < M; ++m) acc[m] = make_float4(0.f, 0.f, 0.f, 0.f);
  const float4* W4 = (const float4*)W;
  for (int k = 0; k < KC; ++k) {
    float4 wv = W4[(size_t)(k0 + k) * nd4 + n4];
#pragma unroll
    for (int m = 0; m < M; ++m) {
      float a = Al[k * M + m];
      acc[m].x += a * wv.x; acc[m].y += a * wv.y; acc[m].z += a * wv.z; acc[m].w += a * wv.w;
    }
  }
  float4* pp = (float4*)(part + ((size_t)blockIdx.y * M) * Nd);
#pragma unroll
  for (int m = 0; m < M; ++m) pp[(size_t)m * nd4 + n4] = acc[m];
}

// ---------------------------------------------------------------- sum 16 partials + bias -> out (M*Nd elements)
__global__ __launch_bounds__(256) void redsum_kernel(const float* __restrict__ part,
                                                     const float* __restrict__ bias,
                                                     float* __restrict__ out, int Nd, int total) {
  int i = blockIdx.x * 256 + threadIdx.x;
  if (i < total) {
    int n = i % Nd;
    float s = bias[n];
#pragma unroll
    for (int c = 0; c < 16; ++c) s += part[(size_t)c * total + i];
    out[i] = s;
  }
}

// ---------------------------------------------------------------- final attention: S=3, dh=1024, 8 heads
__global__ __launch_bounds__(256) void attn3_kernel(const float* __restrict__ qkv, float* __restrict__ o) {
  const int b = blockIdx.x >> 3, h = blockIdx.x & 7;
  const float* base = qkv + (size_t)b * 3 * N3E;
  const int qo = h * 1024, ko = EDIM + h * 1024, vo = 2 * EDIM + h * 1024;
  float p[9] = {};
  for (int d = threadIdx.x; d < 1024; d += 256) {
    float q0 = base[qo + d], q1 = base[N3E + qo + d], q2 = base[2 * N3E + qo + d];
    float k0 = base[ko + d], k1 = base[N3E + ko + d], k2 = base[2 * N3E + ko + d];
    p[0] += q0 * k0; p[1] += q0 * k1; p[2] += q0 * k2;
    p[3] += q1 * k0; p[4] += q1 * k1; p[5] += q1 * k2;
    p[6] += q2 * k0; p[7] += q2 * k1; p[8] += q2 * k2;
  }
  __shared__ float red[4][9];
  __shared__ float aw[9];
  const int lane = threadIdx.x & 63, w = threadIdx.x >> 6;
#pragma unroll
  for (int e = 0; e < 9; ++e)
#pragma unroll
    for (int off = 32; off >= 1; off >>= 1) p[e] += __shfl_xor(p[e], off, 64);
  if (lane == 0)
#pragma unroll
    for (int e = 0; e < 9; ++e) red[w][e] = p[e];
  __syncthreads();
  if (threadIdx.x == 0) {
    float s[9];
#pragma unroll
    for (int e = 0; e < 9; ++e) s[e] = (red[0][e] + red[1][e] + red[2][e] + red[3][e]) / 32.f; // /sqrt(1024)
#pragma unroll
    for (int i = 0; i < 3; ++i) {
      float m = fmaxf(fmaxf(s[i * 3], s[i * 3 + 1]), s[i * 3 + 2]);
      float e0 = expf(s[i * 3] - m), e1 = expf(s[i * 3 + 1] - m), e2 = expf(s[i * 3 + 2] - m);
      float sm = e0 + e1 + e2;
      aw[i * 3] = e0 / sm; aw[i * 3 + 1] = e1 / sm; aw[i * 3 + 2] = e2 / sm;
    }
  }
  __syncthreads();
  for (int d = threadIdx.x; d < 1024; d += 256) {
    float v0 = base[vo + d], v1 = base[N3E + vo + d], v2 = base[2 * N3E + vo + d];
#pragma unroll
    for (int i = 0; i < 3; ++i)
      o[(size_t)(b * 3 + i) * EDIM + h * 1024 + d] = aw[i * 3] * v0 + aw[i * 3 + 1] * v1 + aw[i * 3 + 2] * v2;
  }
}

// ================================================================ launch
extern "C" void kernel_launch(void* const* d_in, const int* in_sizes, int n_in,
                              void* d_out, int out_size, void* d_ws, size_t ws_size,
                              hipStream_t stream) {
  const float* pc      = (const float*)d_in[0];
  const float* pe_w1   = (const float*)d_in[1];
  const float* pe_b1   = (const float*)d_in[2];
  const float* pe_w2   = (const float*)d_in[3];
  const float* pe_b2   = (const float*)d_in[4];
  const float* t_qkv_w = (const float*)d_in[5];
  const float* t_qkv_b = (const float*)d_in[6];
  const float* t_out_w = (const float*)d_in[7];
  const float* t_out_b = (const float*)d_in[8];
  const float* t_ln1_s = (const float*)d_in[9];
  const float* t_ln1_b = (const float*)d_in[10];
  const float* t_ff1_w = (const float*)d_in[11];
  const float* t_ff1_b = (const float*)d_in[12];
  const float* t_ff2_w = (const float*)d_in[13];
  const float* t_ff2_b = (const float*)d_in[14];
  const float* t_ln2_s = (const float*)d_in[15];
  const float* t_ln2_b = (const float*)d_in[16];
  const float* c1_w    = (const float*)d_in[17];
  const float* c1_b    = (const float*)d_in[18];
  const float* c2_w    = (const float*)d_in[19];
  const float* c2_b    = (const float*)d_in[20];
  const float* c3_w    = (const float*)d_in[21];
  const float* c3_b    = (const float*)d_in[22];
  const float* x_qkv_w = (const float*)d_in[23];
  const float* x_qkv_b = (const float*)d_in[24];
  const float* x_out_w = (const float*)d_in[25];
  const float* x_out_b = (const float*)d_in[26];
  float* outp = (float*)d_out;

  // workspace layout (peak dominated by transformer arena; partials alias it)
  char* wsp = (char*)d_ws;
  auto alloc = [&](size_t bytes) { char* q = wsp; wsp += (bytes + 255) & ~(size_t)255; return q; };
  float* centers = (float*)alloc((size_t)NBATCH * KCP * 3 * 4);
  float* pmax    = (float*)alloc(512 * 4);
  float* pmin    = (float*)alloc(512 * 4);
  float* Lv      = (float*)alloc(256);
  unsigned* tags = (unsigned*)alloc((size_t)NBATCH * RING * 64 * 4);                          // 16 KB
  unsigned long long* keyss = (unsigned long long*)alloc((size_t)NBATCH * RING * 64 * GPUB * 8); // 256 KB (adjacent to tags)
  float* x  = (float*)alloc((size_t)4096 * 256 * 4);
  float* xb = (float*)alloc((size_t)4096 * 256 * 4);
  float* arena = (float*)wsp;
  // transformer views
  float* qkvb = arena;
  float* ao   = qkvb + (size_t)4096 * 768;
  float* po   = ao + (size_t)4096 * 256;
  float* ffh  = po + (size_t)4096 * 256;
  float* ffo  = ffh + (size_t)4096 * 1024;
  // post-phase views (alias arena; transformer scratch dead by then)
  float* tri  = arena;
  float* z1   = tri + (size_t)NBATCH * 3 * 256 * 256;
  float* z2   = z1 + (size_t)12 * 512 * 64;
  float* z3   = z2 + (size_t)12 * 1024 * 16;
  float* qkv2 = z3 + (size_t)12 * 8192;
  float* at2  = qkv2 + (size_t)12 * N3E;
  float* mvp  = at2 + (size_t)12 * EDIM;   // 16 x 12 x N3E partials (18.9 MB, < transformer arena)
  (void)in_sizes; (void)n_in; (void)out_size; (void)ws_size; (void)ffo;

  // FPS mailbox must be zero every call (tags poll vs round#; 0 = not ready).
  hipMemsetAsync(tags, 0, (size_t)NBATCH * RING * 64 * 4 + (size_t)NBATCH * RING * 64 * GPUB * 8, stream);

  redmm_kernel<<<512, 256, 0, stream>>>(pc, NBATCH * NPTS * 3, pmax, pmin);
  redfin_kernel<<<1, 256, 0, stream>>>(pmax, pmin, 512, Lv);

  fps_kernel<<<NBATCH * FPS_NBLK, FPS_THR, 0, stream>>>(pc, centers, tags, keyss);

  pe_kernel<<<NBATCH * KCP, 128, 0, stream>>>(centers, pe_w1, pe_b1, pe_w2, pe_b2, x);

  for (int l = 0; l < 2; ++l) {
    gemm_mfma_kernel<<<dim3(6, 32), 256, 0, stream>>>(x, t_qkv_w + (size_t)l * 256 * 768,
                                                      t_qkv_b + (size_t)l * 768, qkvb, 4096, 256, 768, 0);
    flash_mfma_kernel<<<dim3(16, 8, 4), 256, 0, stream>>>(qkvb, ao);
    gemm64_mfma_kernel<<<dim3(2, 64), 128, 0, stream>>>(ao, t_out_w + (size_t)l * 256 * 256,
                                                        t_out_b + (size_t)l * 256, po, 4096, 256, 256, 0);
    ln_kernel<<<1024, 256, 0, stream>>>(x, po, t_ln1_s + (size_t)l * 256, t_ln1_b + (size_t)l * 256, xb);
    gemm_mfma_kernel<<<dim3(8, 32), 256, 0, stream>>>(xb, t_ff1_w + (size_t)l * 256 * 1024,
                                                      t_ff1_b + (size_t)l * 1024, ffh, 4096, 256, 1024, 1);
    gemm64_mfma_kernel<<<dim3(2, 64), 128, 0, stream>>>(ffh, t_ff2_w + (size_t)l * 1024 * 256,
                                                        t_ff2_b + (size_t)l * 256, ffo, 4096, 1024, 256, 0);
    ln_kernel<<<1024, 256, 0, stream>>>(xb, ffo, t_ln2_s + (size_t)l * 256, t_ln2_b + (size_t)l * 256, x);
  }

  // scatter to tri-planes (zero first: atomic accumulation, and arena was reused)
  hipMemsetAsync(tri, 0, (size_t)NBATCH * 3 * 256 * 256 * 4, stream);
  scatter_kernel<<<NBATCH * KCP, 256, 0, stream>>>(x, centers, Lv, tri);

  conv_kernel<256, 512, 16, 16, 8, 8, 4, 32><<<dim3(12, 128), 256, 0, stream>>>(tri, c1_w, c1_b, z1);
  conv_kernel<512, 1024, 8, 8, 4, 4, 16, 128><<<dim3(12, 64), 256, 0, stream>>>(z1, c2_w, c2_b, z2);
  conv3g_kernel<<<2048, 256, 0, stream>>>(z2, c3_w, c3_b, z3);

  // qkv2 = z3 @ x_qkv_w + b : K-split float4 partials (no atomics) + fused reduce
  matvec_part4_kernel<12, 512><<<dim3(N3E / 1024, 16), 256, 0, stream>>>(z3, x_qkv_w, mvp, EDIM, N3E);
  redsum_kernel<<<(12 * N3E + 255) / 256, 256, 0, stream>>>(mvp, x_qkv_b, qkv2, N3E, 12 * N3E);

  attn3_kernel<<<32, 256, 0, stream>>>(qkv2, at2);

  matvec_part4_kernel<12, 512><<<dim3(EDIM / 1024, 16), 256, 0, stream>>>(at2, x_out_w, mvp, EDIM, EDIM);
  redsum_kernel<<<(12 * EDIM + 255) / 256, 256, 0, stream>>>(mvp, x_out_b, outp, EDIM, 12 * EDIM);
}